// Round 1
// baseline (2167.362 us; speedup 1.0000x reference)
//
#include <hip/hip_runtime.h>
#include <math.h>

#define NB 4
#define SEQ 4096
#define HID 2048
#define DH 256
#define DV 512
#define CHUNK 128
#define NCH 32                  // SEQ/CHUNK
// log2(0.96875)
#define LOG2_GAMMA (-0.045803689613124794f)
// log2(10000)
#define LOG2_10000 13.287712379549449f

// ---------------------------------------------------------------------------
// Kernel 1: fused QKV projection + xPos rotary/scale epilogue.
// C = X @ [W_Q | W_K | W_V]  (M=16384, K=2048, N=1024), 128x128 tile, BK=16,
// 256 threads, 8x8 micro-tile. n-tile boundaries align with Q/K/V regions.
// ---------------------------------------------------------------------------
__global__ __launch_bounds__(256) void qkv_xpos_kernel(
    const float* __restrict__ X, const float* __restrict__ WQ,
    const float* __restrict__ WK, const float* __restrict__ WV,
    float* __restrict__ Qw, float* __restrict__ Kw, float* __restrict__ Vw)
{
    __shared__ float As[16][132];   // transposed: As[k][m]
    __shared__ float Bs[16][132];   // natural:    Bs[k][n]

    const int bid = blockIdx.x;
    const int nt = bid & 7;        // 8 n-tiles
    const int mt = bid >> 3;       // 128 m-tiles
    const int m0 = mt * 128;
    const int n0 = nt * 128;

    const float* Wb; int ldb; int c0; int region;  // 0=Q,1=K,2=V
    if (n0 < 256)      { Wb = WQ; ldb = DH; c0 = n0;       region = 0; }
    else if (n0 < 512) { Wb = WK; ldb = DH; c0 = n0 - 256; region = 1; }
    else               { Wb = WV; ldb = DV; c0 = n0 - 512; region = 2; }

    const int t = threadIdx.x;
    const int tx = t & 15, ty = t >> 4;

    float acc[8][8];
#pragma unroll
    for (int i = 0; i < 8; i++)
#pragma unroll
        for (int j = 0; j < 8; j++) acc[i][j] = 0.f;

    const int ar = t >> 2;            // A: row within tile (0..63, +64)
    const int ac = (t & 3) << 2;      // A: k-col group
    const int br = t >> 5;            // B: k-row (0..7, +8)
    const int bc = (t & 31) << 2;     // B: n-col group

    for (int k0 = 0; k0 < HID; k0 += 16) {
        float4 a0 = *(const float4*)&X[(size_t)(m0 + ar) * HID + k0 + ac];
        float4 a1 = *(const float4*)&X[(size_t)(m0 + ar + 64) * HID + k0 + ac];
        float4 b0 = *(const float4*)&Wb[(size_t)(k0 + br) * ldb + c0 + bc];
        float4 b1 = *(const float4*)&Wb[(size_t)(k0 + br + 8) * ldb + c0 + bc];
        __syncthreads();   // previous iteration's compute done
        As[ac + 0][ar] = a0.x; As[ac + 1][ar] = a0.y;
        As[ac + 2][ar] = a0.z; As[ac + 3][ar] = a0.w;
        As[ac + 0][ar + 64] = a1.x; As[ac + 1][ar + 64] = a1.y;
        As[ac + 2][ar + 64] = a1.z; As[ac + 3][ar + 64] = a1.w;
        *(float4*)&Bs[br][bc] = b0;
        *(float4*)&Bs[br + 8][bc] = b1;
        __syncthreads();
#pragma unroll
        for (int k = 0; k < 16; k++) {
            float af[8], bf[8];
            *(float4*)&af[0] = *(const float4*)&As[k][ty * 8];
            *(float4*)&af[4] = *(const float4*)&As[k][ty * 8 + 4];
            *(float4*)&bf[0] = *(const float4*)&Bs[k][tx * 8];
            *(float4*)&bf[4] = *(const float4*)&Bs[k][tx * 8 + 4];
#pragma unroll
            for (int i = 0; i < 8; i++)
#pragma unroll
                for (int j = 0; j < 8; j++) acc[i][j] += af[i] * bf[j];
        }
    }

    const int mrow = m0 + ty * 8;
    const int ncol = c0 + tx * 8;   // local column within region
    if (region == 2) {
#pragma unroll
        for (int i = 0; i < 8; i++) {
            const int m = mrow + i;
            *(float4*)&Vw[(size_t)m * DV + ncol] =
                make_float4(acc[i][0], acc[i][1], acc[i][2], acc[i][3]);
            *(float4*)&Vw[(size_t)m * DV + ncol + 4] =
                make_float4(acc[i][4], acc[i][5], acc[i][6], acc[i][7]);
        }
    } else {
        float* dst = (region == 0) ? Qw : Kw;
        const float sgn = (region == 0) ? 1.f : -1.f;   // K is downscaled
        float l2sv[4], invf[4];
#pragma unroll
        for (int jp = 0; jp < 4; jp++) {
            const float jj = (float)((ncol >> 1) + jp);       // pair index 0..127
            const float sv = (2.f * jj + 0.4f * 256.f) * (1.f / (1.4f * 256.f));
            l2sv[jp] = log2f(sv) * sgn * (1.f / 512.f);        // per-pos exponent coeff
            invf[jp] = exp2f(jj * (-LOG2_10000 / 128.f));      // 1/10000^(jj/128)
        }
#pragma unroll
        for (int i = 0; i < 8; i++) {
            const int m = mrow + i;
            const float s = (float)(m & (SEQ - 1));            // position
            float o[8];
#pragma unroll
            for (int jp = 0; jp < 4; jp++) {
                const float sc = exp2f(s * l2sv[jp]);          // scale^(±s/512)
                const float ang = s * invf[jp];
                const float sn = sinf(ang), cs = cosf(ang);
                const float x0 = acc[i][2 * jp], x1 = acc[i][2 * jp + 1];
                o[2 * jp]     = sc * (x0 * cs - x1 * sn);
                o[2 * jp + 1] = sc * (x1 * cs + x0 * sn);
            }
            *(float4*)&dst[(size_t)m * DH + ncol] = make_float4(o[0], o[1], o[2], o[3]);
            *(float4*)&dst[(size_t)m * DH + ncol + 4] = make_float4(o[4], o[5], o[6], o[7]);
        }
    }
}

// ---------------------------------------------------------------------------
// Kernel 2: per-chunk U_c = K^T diag(gamma^(C-i)) V   (256x512 per (b,c)).
// Block computes a 128x128 sub-tile; grid = b(4) * c(32) * dh-tile(2) * dv(4).
// ---------------------------------------------------------------------------
__global__ __launch_bounds__(256) void chunk_kv_kernel(
    const float* __restrict__ Kw, const float* __restrict__ Vw,
    float* __restrict__ Uw)
{
    __shared__ float kls[32][132];   // [i_local][dh_local], pre-scaled
    __shared__ float vls[32][132];   // [i_local][dv_local]

    const int bid = blockIdx.x;      // 1024
    const int vq = bid & 3;
    const int ht = (bid >> 2) & 1;
    const int c  = (bid >> 3) & 31;
    const int b  = bid >> 8;
    const int dh0 = ht * 128, dv0 = vq * 128;
    const int t = threadIdx.x, tx = t & 15, ty = t >> 4;

    float acc[8][8];
#pragma unroll
    for (int i = 0; i < 8; i++)
#pragma unroll
        for (int j = 0; j < 8; j++) acc[i][j] = 0.f;

    const int lr = t >> 5;            // 0..7, 4 passes
    const int lc = (t & 31) << 2;

    for (int i0 = 0; i0 < CHUNK; i0 += 32) {
        __syncthreads();
#pragma unroll
        for (int p = 0; p < 4; p++) {
            const int il = lr + 8 * p;
            const int i = i0 + il;
            const int row = b * SEQ + c * CHUNK + i;
            const float w = exp2f((float)(CHUNK - i) * LOG2_GAMMA);  // gamma^(C-i)
            float4 kv = *(const float4*)&Kw[(size_t)row * DH + dh0 + lc];
            kv.x *= w; kv.y *= w; kv.z *= w; kv.w *= w;
            *(float4*)&kls[il][lc] = kv;
            *(float4*)&vls[il][lc] = *(const float4*)&Vw[(size_t)row * DV + dv0 + lc];
        }
        __syncthreads();
#pragma unroll
        for (int i = 0; i < 32; i++) {
            float af[8], bf[8];
            *(float4*)&af[0] = *(const float4*)&kls[i][ty * 8];
            *(float4*)&af[4] = *(const float4*)&kls[i][ty * 8 + 4];
            *(float4*)&bf[0] = *(const float4*)&vls[i][tx * 8];
            *(float4*)&bf[4] = *(const float4*)&vls[i][tx * 8 + 4];
#pragma unroll
            for (int ii = 0; ii < 8; ii++)
#pragma unroll
                for (int jj = 0; jj < 8; jj++) acc[ii][jj] += af[ii] * bf[jj];
        }
    }

    const size_t ub = ((size_t)(b * NCH + c) * DH + dh0 + ty * 8) * DV + dv0 + tx * 8;
#pragma unroll
    for (int ii = 0; ii < 8; ii++) {
        *(float4*)&Uw[ub + (size_t)ii * DV] =
            make_float4(acc[ii][0], acc[ii][1], acc[ii][2], acc[ii][3]);
        *(float4*)&Uw[ub + (size_t)ii * DV + 4] =
            make_float4(acc[ii][4], acc[ii][5], acc[ii][6], acc[ii][7]);
    }
}

// ---------------------------------------------------------------------------
// Kernel 3: in-place exclusive scan over chunks: S_c = state BEFORE chunk c.
// s=0; for c: u=U[c]; U[c]=s; s = gamma^C * s + u.  One thread per (b,dh,dv).
// ---------------------------------------------------------------------------
__global__ __launch_bounds__(256) void scan_kernel(float* __restrict__ Uw)
{
    const int t = blockIdx.x * 256 + threadIdx.x;   // 0..524287
    const int b = t >> 17;                          // DH*DV = 131072
    const int r = t & 131071;
    const float gC = exp2f((float)CHUNK * LOG2_GAMMA);   // gamma^128
    float s = 0.f;
    const size_t base = (size_t)b * NCH * 131072 + r;
    for (int c = 0; c < NCH; c++) {
        const size_t off = base + (size_t)c * 131072;
        const float u = Uw[off];
        Uw[off] = s;
        s = gC * s + u;
    }
}

// ---------------------------------------------------------------------------
// Kernel 4: O = intra(tril(QK^T) .* gamma^(i-j)) @ V + gamma^i * Q @ S_c.
// Block = (b, chunk, dv-quarter): O tile 128x128. 256 threads.
// ---------------------------------------------------------------------------
__global__ __launch_bounds__(256) void out_kernel(
    const float* __restrict__ Qw, const float* __restrict__ Kw,
    const float* __restrict__ Vw, const float* __restrict__ Sw,
    float* __restrict__ out)
{
    __shared__ float qT[32][132];    // [d][i] transposed Q (cross: pre-scaled)
    __shared__ float kT[32][36];     // [d][j_local] transposed K (32 j's)
    __shared__ float scT[32][132];   // [j_local][i] decayed scores
    __shared__ float bls[32][132];   // V rows [j][n]; cross: S rows [d][n]

    const int bid = blockIdx.x;      // 512
    const int vq = bid & 3;
    const int c  = (bid >> 2) & 31;
    const int b  = bid >> 7;
    const int dv0 = vq * 128;
    const int row0 = b * SEQ + c * CHUNK;
    const int t = threadIdx.x, tx = t & 15, ty = t >> 4;

    float acc[8][8];
#pragma unroll
    for (int i = 0; i < 8; i++)
#pragma unroll
        for (int j = 0; j < 8; j++) acc[i][j] = 0.f;

    const int ir = t >> 3;           // 0..31 (staging row)
    const int dg = (t & 7) << 2;     // d-col group
    const int vr = t >> 5;           // 0..7 (V/S staging row, 4 passes)
    const int vc = (t & 31) << 2;

    // ---------------- intra-chunk ----------------
    for (int j0 = 0; j0 < CHUNK; j0 += 32) {
        float accs[8][2];
#pragma unroll
        for (int ii = 0; ii < 8; ii++) { accs[ii][0] = 0.f; accs[ii][1] = 0.f; }

        for (int d0 = 0; d0 < DH; d0 += 32) {
            __syncthreads();
#pragma unroll
            for (int p = 0; p < 4; p++) {
                const int i = ir + 32 * p;
                float4 q = *(const float4*)&Qw[(size_t)(row0 + i) * DH + d0 + dg];
                qT[dg + 0][i] = q.x; qT[dg + 1][i] = q.y;
                qT[dg + 2][i] = q.z; qT[dg + 3][i] = q.w;
            }
            {
                float4 kv = *(const float4*)&Kw[(size_t)(row0 + j0 + ir) * DH + d0 + dg];
                kT[dg + 0][ir] = kv.x; kT[dg + 1][ir] = kv.y;
                kT[dg + 2][ir] = kv.z; kT[dg + 3][ir] = kv.w;
            }
            __syncthreads();
#pragma unroll
            for (int dd = 0; dd < 32; dd++) {
                float af[8];
                *(float4*)&af[0] = *(const float4*)&qT[dd][ty * 8];
                *(float4*)&af[4] = *(const float4*)&qT[dd][ty * 8 + 4];
                const float b0 = kT[dd][tx * 2], b1 = kT[dd][tx * 2 + 1];
#pragma unroll
                for (int ii = 0; ii < 8; ii++) {
                    accs[ii][0] += af[ii] * b0;
                    accs[ii][1] += af[ii] * b1;
                }
            }
        }
        // decay mask + write transposed scores
        __syncthreads();
#pragma unroll
        for (int jj = 0; jj < 2; jj++) {
            const int j = j0 + tx * 2 + jj;
#pragma unroll
            for (int ii = 0; ii < 8; ii++) {
                const int i = ty * 8 + ii;
                const int diff = i - j;
                scT[tx * 2 + jj][i] =
                    (diff >= 0) ? accs[ii][jj] * exp2f((float)diff * LOG2_GAMMA) : 0.f;
            }
        }
        // stage V rows j0..j0+31
#pragma unroll
        for (int p = 0; p < 4; p++) {
            const int jl = vr + 8 * p;
            *(float4*)&bls[jl][vc] =
                *(const float4*)&Vw[(size_t)(row0 + j0 + jl) * DV + dv0 + vc];
        }
        __syncthreads();
#pragma unroll
        for (int jr = 0; jr < 32; jr++) {
            float af[8], bf[8];
            *(float4*)&af[0] = *(const float4*)&scT[jr][ty * 8];
            *(float4*)&af[4] = *(const float4*)&scT[jr][ty * 8 + 4];
            *(float4*)&bf[0] = *(const float4*)&bls[jr][tx * 8];
            *(float4*)&bf[4] = *(const float4*)&bls[jr][tx * 8 + 4];
#pragma unroll
            for (int ii = 0; ii < 8; ii++)
#pragma unroll
                for (int jj = 0; jj < 8; jj++) acc[ii][jj] += af[ii] * bf[jj];
        }
    }

    // ---------------- cross term: gamma^i * Q @ S_c ----------------
    const size_t sbase = (size_t)(b * NCH + c) * (DH * DV);
    for (int d0 = 0; d0 < DH; d0 += 32) {
        __syncthreads();
#pragma unroll
        for (int p = 0; p < 4; p++) {
            const int i = ir + 32 * p;
            const float g = exp2f((float)i * LOG2_GAMMA);   // gamma^i
            float4 q = *(const float4*)&Qw[(size_t)(row0 + i) * DH + d0 + dg];
            qT[dg + 0][i] = q.x * g; qT[dg + 1][i] = q.y * g;
            qT[dg + 2][i] = q.z * g; qT[dg + 3][i] = q.w * g;
        }
#pragma unroll
        for (int p = 0; p < 4; p++) {
            const int dr = vr + 8 * p;
            *(float4*)&bls[dr][vc] =
                *(const float4*)&Sw[sbase + (size_t)(d0 + dr) * DV + dv0 + vc];
        }
        __syncthreads();
#pragma unroll
        for (int dd = 0; dd < 32; dd++) {
            float af[8], bf[8];
            *(float4*)&af[0] = *(const float4*)&qT[dd][ty * 8];
            *(float4*)&af[4] = *(const float4*)&qT[dd][ty * 8 + 4];
            *(float4*)&bf[0] = *(const float4*)&bls[dd][tx * 8];
            *(float4*)&bf[4] = *(const float4*)&bls[dd][tx * 8 + 4];
#pragma unroll
            for (int ii = 0; ii < 8; ii++)
#pragma unroll
                for (int jj = 0; jj < 8; jj++) acc[ii][jj] += af[ii] * bf[jj];
        }
    }

    // store O tile
#pragma unroll
    for (int ii = 0; ii < 8; ii++) {
        const int i = ty * 8 + ii;
        float* dst = &out[(size_t)(row0 + i) * DV + dv0 + tx * 8];
        *(float4*)&dst[0] = make_float4(acc[ii][0], acc[ii][1], acc[ii][2], acc[ii][3]);
        *(float4*)&dst[4] = make_float4(acc[ii][4], acc[ii][5], acc[ii][6], acc[ii][7]);
    }
}

// ---------------------------------------------------------------------------
extern "C" void kernel_launch(void* const* d_in, const int* in_sizes, int n_in,
                              void* d_out, int out_size, void* d_ws, size_t ws_size,
                              hipStream_t stream) {
    const float* X  = (const float*)d_in[0];
    const float* WQ = (const float*)d_in[1];
    const float* WK = (const float*)d_in[2];
    const float* WV = (const float*)d_in[3];
    float* out = (float*)d_out;

    // Workspace layout (floats): Q 4.19M | K 4.19M | V 8.39M | U/S 16.78M
    // = 134.2 MB total.
    float* ws = (float*)d_ws;
    float* Qw = ws;
    float* Kw = Qw + (size_t)NB * SEQ * DH;
    float* Vw = Kw + (size_t)NB * SEQ * DH;
    float* Uw = Vw + (size_t)NB * SEQ * DV;

    qkv_xpos_kernel<<<1024, 256, 0, stream>>>(X, WQ, WK, WV, Qw, Kw, Vw);
    chunk_kv_kernel<<<1024, 256, 0, stream>>>(Kw, Vw, Uw);
    scan_kernel<<<2048, 256, 0, stream>>>(Uw);
    out_kernel<<<512, 256, 0, stream>>>(Qw, Kw, Vw, Uw, out);
}

// Round 2
// 1470.645 us; speedup vs baseline: 1.4737x; 1.4737x over previous
//
#include <hip/hip_runtime.h>
#include <math.h>

#define NB 4
#define SEQ 4096
#define HID 2048
#define DH 256
#define DV 512
#define NQKV 1024               // DH + DH + DV packed
#define CHUNK 128
#define NCH 32                  // SEQ/CHUNK
// log2(0.96875)
#define LOG2_GAMMA (-0.045803689613124794f)
// log2(10000)
#define LOG2_10000 13.287712379549449f

typedef __attribute__((ext_vector_type(8))) short short8;
typedef __attribute__((ext_vector_type(4))) float floatx4;

// ---------------------------------------------------------------------------
// helpers
// ---------------------------------------------------------------------------
__device__ __forceinline__ unsigned short bf16_rne(float v) {
    unsigned int u = __float_as_uint(v);
    u += 0x7fff + ((u >> 16) & 1);
    return (unsigned short)(u >> 16);
}

// async global->LDS, 16 bytes per lane. LDS dest = wave-uniform base + lane*16.
__device__ __forceinline__ void gld16(const void* g, void* l) {
    __builtin_amdgcn_global_load_lds(
        reinterpret_cast<const __attribute__((address_space(1))) unsigned int*>(
            reinterpret_cast<uintptr_t>(g)),
        reinterpret_cast<__attribute__((address_space(3))) unsigned int*>(
            reinterpret_cast<uintptr_t>(l)),
        16, 0, 0);
}

// ---------------------------------------------------------------------------
// Kernel 0a: X fp32 -> Xhi/Xlo bf16 (split precision), row-major [M][K].
// ---------------------------------------------------------------------------
__global__ __launch_bounds__(256) void xcvt_kernel(
    const float* __restrict__ X, unsigned short* __restrict__ Xhi,
    unsigned short* __restrict__ Xlo)
{
    const int i = blockIdx.x * 256 + threadIdx.x;   // one float4 per thread
    float4 x = ((const float4*)X)[i];
    ushort4 h, l;
    {
        h.x = bf16_rne(x.x); l.x = bf16_rne(x.x - __uint_as_float((unsigned)h.x << 16));
        h.y = bf16_rne(x.y); l.y = bf16_rne(x.y - __uint_as_float((unsigned)h.y << 16));
        h.z = bf16_rne(x.z); l.z = bf16_rne(x.z - __uint_as_float((unsigned)h.z << 16));
        h.w = bf16_rne(x.w); l.w = bf16_rne(x.w - __uint_as_float((unsigned)h.w << 16));
    }
    ((ushort4*)Xhi)[i] = h;
    ((ushort4*)Xlo)[i] = l;
}

// ---------------------------------------------------------------------------
// Kernel 0b: W_Q|W_K|W_V fp32 [K][N-region] -> transposed packed bf16 hi/lo
// Bt[n][k], n in 0..1023 (Q cols 0-255, K 256-511, V 512-1023), k in 0..2047.
// 64x64 tile transpose through LDS.
// ---------------------------------------------------------------------------
__global__ __launch_bounds__(256) void wcvt_kernel(
    const float* __restrict__ WQ, const float* __restrict__ WK,
    const float* __restrict__ WV, unsigned short* __restrict__ Bhi,
    unsigned short* __restrict__ Blo)
{
    __shared__ unsigned short sh[64][65];
    __shared__ unsigned short sl[64][65];
    const int bid = blockIdx.x;         // 32 k-tiles * 16 n-tiles
    const int kt = bid & 31;
    const int ntile = bid >> 5;
    const int k0 = kt * 64, n0 = ntile * 64;

    const float* W; int ld, nl0;
    if (n0 < 256)      { W = WQ; ld = DH; nl0 = n0; }
    else if (n0 < 512) { W = WK; ld = DH; nl0 = n0 - 256; }
    else               { W = WV; ld = DV; nl0 = n0 - 512; }

    const int t = threadIdx.x;
#pragma unroll
    for (int p = 0; p < 4; p++) {
        const int kl = (t >> 4) + p * 16;
        const int ng = (t & 15) * 4;
        float4 w = *(const float4*)&W[(size_t)(k0 + kl) * ld + nl0 + ng];
        sh[kl][ng + 0] = bf16_rne(w.x);
        sl[kl][ng + 0] = bf16_rne(w.x - __uint_as_float((unsigned)sh[kl][ng + 0] << 16));
        sh[kl][ng + 1] = bf16_rne(w.y);
        sl[kl][ng + 1] = bf16_rne(w.y - __uint_as_float((unsigned)sh[kl][ng + 1] << 16));
        sh[kl][ng + 2] = bf16_rne(w.z);
        sl[kl][ng + 2] = bf16_rne(w.z - __uint_as_float((unsigned)sh[kl][ng + 2] << 16));
        sh[kl][ng + 3] = bf16_rne(w.w);
        sl[kl][ng + 3] = bf16_rne(w.w - __uint_as_float((unsigned)sh[kl][ng + 3] << 16));
    }
    __syncthreads();
#pragma unroll
    for (int p = 0; p < 4; p++) {
        const int nl = (t >> 4) + p * 16;
        const int kg = (t & 15) * 4;
        ushort4 h, l;
        h.x = sh[kg + 0][nl]; h.y = sh[kg + 1][nl];
        h.z = sh[kg + 2][nl]; h.w = sh[kg + 3][nl];
        l.x = sl[kg + 0][nl]; l.y = sl[kg + 1][nl];
        l.z = sl[kg + 2][nl]; l.w = sl[kg + 3][nl];
        *(ushort4*)&Bhi[(size_t)(n0 + nl) * HID + k0 + kg] = h;
        *(ushort4*)&Blo[(size_t)(n0 + nl) * HID + k0 + kg] = l;
    }
}

// ---------------------------------------------------------------------------
// Kernel 1: QKV projection via split-bf16 MFMA + xPos epilogue.
// C = X @ [W_Q|W_K|W_V], M=16384, N=1024, K=2048.
// 128x128 tile, BK=32, 4 waves (each 64x64 = 4x4 MFMA 16x16x32 tiles).
// Split products: ah*bh + ah*bl + al*bh (rel err ~2^-16).
// ---------------------------------------------------------------------------
__global__ __launch_bounds__(256, 2) void qkv_mfma_kernel(
    const unsigned short* __restrict__ Xhi, const unsigned short* __restrict__ Xlo,
    const unsigned short* __restrict__ Bhi, const unsigned short* __restrict__ Blo,
    float* __restrict__ Qw, float* __restrict__ Kw, float* __restrict__ Vw)
{
    __shared__ unsigned short Ah[128 * 32];
    __shared__ unsigned short Al[128 * 32];
    __shared__ unsigned short Bh[128 * 32];
    __shared__ unsigned short Bl[128 * 32];

    const int bid = blockIdx.x;
    const int nt = bid & 7;          // 8 n-tiles
    const int mt = bid >> 3;         // 128 m-tiles
    const int m0 = mt * 128, n0 = nt * 128;

    const int t = threadIdx.x;
    const int w = t >> 6, lane = t & 63;

    floatx4 acc[4][4];
#pragma unroll
    for (int i = 0; i < 4; i++)
#pragma unroll
        for (int j = 0; j < 4; j++) acc[i][j] = (floatx4)0.0f;

    // staging source addresses (elements). lane i -> row i/4, cols (i%4)*8..+8
    const size_t aoff = (size_t)(m0 + w * 16 + (lane >> 2)) * HID + (lane & 3) * 8;
    const size_t boff = (size_t)(n0 + w * 16 + (lane >> 2)) * HID + (lane & 3) * 8;
    unsigned short* const ldsA0 = &Ah[(w * 16) * 32];
    unsigned short* const ldsA1 = &Ah[(64 + w * 16) * 32];
    unsigned short* const ldsAl0 = &Al[(w * 16) * 32];
    unsigned short* const ldsAl1 = &Al[(64 + w * 16) * 32];
    unsigned short* const ldsB0 = &Bh[(w * 16) * 32];
    unsigned short* const ldsB1 = &Bh[(64 + w * 16) * 32];
    unsigned short* const ldsBl0 = &Bl[(w * 16) * 32];
    unsigned short* const ldsBl1 = &Bl[(64 + w * 16) * 32];

    const int wm = (w & 1) << 6, wn = (w >> 1) << 6;
    const int fr = lane & 15, fq = (lane >> 4) * 8;

    for (int k0 = 0; k0 < HID; k0 += 32) {
        __syncthreads();   // prior iteration's LDS reads done
        gld16(Xhi + aoff + k0, ldsA0);
        gld16(Xhi + aoff + 64 * HID + k0, ldsA1);
        gld16(Xlo + aoff + k0, ldsAl0);
        gld16(Xlo + aoff + 64 * HID + k0, ldsAl1);
        gld16(Bhi + boff + k0, ldsB0);
        gld16(Bhi + boff + 64 * HID + k0, ldsB1);
        gld16(Blo + boff + k0, ldsBl0);
        gld16(Blo + boff + 64 * HID + k0, ldsBl1);
        __syncthreads();   // compiler drains vmcnt(0) before barrier

        short8 ah[4], al[4], bh[4], bl[4];
#pragma unroll
        for (int i = 0; i < 4; i++) {
            const int ra = (wm + i * 16 + fr) * 32 + fq;
            ah[i] = *(const short8*)&Ah[ra];
            al[i] = *(const short8*)&Al[ra];
            const int rb = (wn + i * 16 + fr) * 32 + fq;
            bh[i] = *(const short8*)&Bh[rb];
            bl[i] = *(const short8*)&Bl[rb];
        }
#pragma unroll
        for (int i = 0; i < 4; i++)
#pragma unroll
            for (int j = 0; j < 4; j++) {
                acc[i][j] = __builtin_amdgcn_mfma_f32_16x16x32_bf16(ah[i], bh[j], acc[i][j], 0, 0, 0);
                acc[i][j] = __builtin_amdgcn_mfma_f32_16x16x32_bf16(ah[i], bl[j], acc[i][j], 0, 0, 0);
                acc[i][j] = __builtin_amdgcn_mfma_f32_16x16x32_bf16(al[i], bh[j], acc[i][j], 0, 0, 0);
            }
    }

    // epilogue. C/D layout: col = lane&15, row = (lane>>4)*4 + reg.
    const int cl = lane & 15, rq = (lane >> 4) << 2;
    if (n0 >= 512) {
        const int c0v = n0 - 512 + wn;
#pragma unroll
        for (int i = 0; i < 4; i++)
#pragma unroll
            for (int j = 0; j < 4; j++) {
                const int c = c0v + j * 16 + cl;
#pragma unroll
                for (int r = 0; r < 4; r++) {
                    const int m = m0 + wm + i * 16 + rq + r;
                    Vw[(size_t)m * DV + c] = acc[i][j][r];
                }
            }
    } else {
        float* dst = (n0 < 256) ? Qw : Kw;
        const float sgn = (n0 < 256) ? 1.f : -1.f;     // K downscaled
        const int nb = (n0 < 256) ? n0 : n0 - 256;
#pragma unroll
        for (int j = 0; j < 4; j++) {
            const int c = nb + wn + j * 16 + cl;
            const float jj = (float)(c >> 1);
            const float sv = (2.f * jj + 0.4f * 256.f) * (1.f / (1.4f * 256.f));
            const float l2sv = log2f(sv) * sgn * (1.f / 512.f);
            const float invf = exp2f(jj * (-LOG2_10000 / 128.f));
            const bool odd = (c & 1) != 0;
#pragma unroll
            for (int i = 0; i < 4; i++) {
#pragma unroll
                for (int r = 0; r < 4; r++) {
                    const int m = m0 + wm + i * 16 + rq + r;
                    const float s = (float)(m & (SEQ - 1));
                    const float x = acc[i][j][r];
                    const float p = __shfl_xor(x, 1, 64);   // rotation partner (c^1)
                    const float sc = exp2f(s * l2sv);
                    const float ang = s * invf;
                    const float sn = sinf(ang), cs = cosf(ang);
                    dst[(size_t)m * DH + c] = odd ? sc * (x * cs + p * sn)
                                                  : sc * (x * cs - p * sn);
                }
            }
        }
    }
}

// ---------------------------------------------------------------------------
// Kernel 2: per-chunk U_c = K^T diag(gamma^(C-i)) V   (256x512 per (b,c)).
// ---------------------------------------------------------------------------
__global__ __launch_bounds__(256, 1) void chunk_kv_kernel(
    const float* __restrict__ Kw, const float* __restrict__ Vw,
    float* __restrict__ Uw)
{
    __shared__ float kls[32][132];
    __shared__ float vls[32][132];

    const int bid = blockIdx.x;      // 1024
    const int vq = bid & 3;
    const int ht = (bid >> 2) & 1;
    const int c  = (bid >> 3) & 31;
    const int b  = bid >> 8;
    const int dh0 = ht * 128, dv0 = vq * 128;
    const int t = threadIdx.x, tx = t & 15, ty = t >> 4;

    float acc[8][8];
#pragma unroll
    for (int i = 0; i < 8; i++)
#pragma unroll
        for (int j = 0; j < 8; j++) acc[i][j] = 0.f;

    const int lr = t >> 5;
    const int lc = (t & 31) << 2;

    for (int i0 = 0; i0 < CHUNK; i0 += 32) {
        __syncthreads();
#pragma unroll
        for (int p = 0; p < 4; p++) {
            const int il = lr + 8 * p;
            const int i = i0 + il;
            const int row = b * SEQ + c * CHUNK + i;
            const float wgt = exp2f((float)(CHUNK - i) * LOG2_GAMMA);
            float4 kv = *(const float4*)&Kw[(size_t)row * DH + dh0 + lc];
            kv.x *= wgt; kv.y *= wgt; kv.z *= wgt; kv.w *= wgt;
            *(float4*)&kls[il][lc] = kv;
            *(float4*)&vls[il][lc] = *(const float4*)&Vw[(size_t)row * DV + dv0 + lc];
        }
        __syncthreads();
#pragma unroll
        for (int i = 0; i < 32; i++) {
            float af[8], bf[8];
            *(float4*)&af[0] = *(const float4*)&kls[i][ty * 8];
            *(float4*)&af[4] = *(const float4*)&kls[i][ty * 8 + 4];
            *(float4*)&bf[0] = *(const float4*)&vls[i][tx * 8];
            *(float4*)&bf[4] = *(const float4*)&vls[i][tx * 8 + 4];
#pragma unroll
            for (int ii = 0; ii < 8; ii++)
#pragma unroll
                for (int jj = 0; jj < 8; jj++) acc[ii][jj] += af[ii] * bf[jj];
        }
    }

    const size_t ub = ((size_t)(b * NCH + c) * DH + dh0 + ty * 8) * DV + dv0 + tx * 8;
#pragma unroll
    for (int ii = 0; ii < 8; ii++) {
        *(float4*)&Uw[ub + (size_t)ii * DV] =
            make_float4(acc[ii][0], acc[ii][1], acc[ii][2], acc[ii][3]);
        *(float4*)&Uw[ub + (size_t)ii * DV + 4] =
            make_float4(acc[ii][4], acc[ii][5], acc[ii][6], acc[ii][7]);
    }
}

// ---------------------------------------------------------------------------
// Kernel 3: exclusive scan over chunks: U[c] <- S_c (state BEFORE chunk c).
// ---------------------------------------------------------------------------
__global__ __launch_bounds__(256) void scan_kernel(float* __restrict__ Uw)
{
    const int t = blockIdx.x * 256 + threadIdx.x;   // 0..524287
    const int b = t >> 17;                          // DH*DV = 131072
    const int r = t & 131071;
    const float gC = exp2f((float)CHUNK * LOG2_GAMMA);
    float s = 0.f;
    const size_t base = (size_t)b * NCH * 131072 + r;
    for (int c = 0; c < NCH; c++) {
        const size_t off = base + (size_t)c * 131072;
        const float u = Uw[off];
        Uw[off] = s;
        s = gC * s + u;
    }
}

// ---------------------------------------------------------------------------
// Kernel 4: O = intra(tril(QK^T) .* gamma^(i-j)) @ V + gamma^i * Q @ S_c.
// ---------------------------------------------------------------------------
__global__ __launch_bounds__(256, 1) void out_kernel(
    const float* __restrict__ Qw, const float* __restrict__ Kw,
    const float* __restrict__ Vw, const float* __restrict__ Sw,
    float* __restrict__ out)
{
    __shared__ float qT[32][132];
    __shared__ float kT[32][36];
    __shared__ float scT[32][132];
    __shared__ float bls[32][132];

    const int bid = blockIdx.x;      // 512
    const int vq = bid & 3;
    const int c  = (bid >> 2) & 31;
    const int b  = bid >> 7;
    const int dv0 = vq * 128;
    const int row0 = b * SEQ + c * CHUNK;
    const int t = threadIdx.x, tx = t & 15, ty = t >> 4;

    float acc[8][8];
#pragma unroll
    for (int i = 0; i < 8; i++)
#pragma unroll
        for (int j = 0; j < 8; j++) acc[i][j] = 0.f;

    const int ir = t >> 3;
    const int dg = (t & 7) << 2;
    const int vr = t >> 5;
    const int vc = (t & 31) << 2;

    for (int j0 = 0; j0 < CHUNK; j0 += 32) {
        float accs[8][2];
#pragma unroll
        for (int ii = 0; ii < 8; ii++) { accs[ii][0] = 0.f; accs[ii][1] = 0.f; }

        for (int d0 = 0; d0 < DH; d0 += 32) {
            __syncthreads();
#pragma unroll
            for (int p = 0; p < 4; p++) {
                const int i = ir + 32 * p;
                float4 q = *(const float4*)&Qw[(size_t)(row0 + i) * DH + d0 + dg];
                qT[dg + 0][i] = q.x; qT[dg + 1][i] = q.y;
                qT[dg + 2][i] = q.z; qT[dg + 3][i] = q.w;
            }
            {
                float4 kv = *(const float4*)&Kw[(size_t)(row0 + j0 + ir) * DH + d0 + dg];
                kT[dg + 0][ir] = kv.x; kT[dg + 1][ir] = kv.y;
                kT[dg + 2][ir] = kv.z; kT[dg + 3][ir] = kv.w;
            }
            __syncthreads();
#pragma unroll
            for (int dd = 0; dd < 32; dd++) {
                float af[8];
                *(float4*)&af[0] = *(const float4*)&qT[dd][ty * 8];
                *(float4*)&af[4] = *(const float4*)&qT[dd][ty * 8 + 4];
                const float b0 = kT[dd][tx * 2], b1 = kT[dd][tx * 2 + 1];
#pragma unroll
                for (int ii = 0; ii < 8; ii++) {
                    accs[ii][0] += af[ii] * b0;
                    accs[ii][1] += af[ii] * b1;
                }
            }
        }
        __syncthreads();
#pragma unroll
        for (int jj = 0; jj < 2; jj++) {
            const int j = j0 + tx * 2 + jj;
#pragma unroll
            for (int ii = 0; ii < 8; ii++) {
                const int i = ty * 8 + ii;
                const int diff = i - j;
                scT[tx * 2 + jj][i] =
                    (diff >= 0) ? accs[ii][jj] * exp2f((float)diff * LOG2_GAMMA) : 0.f;
            }
        }
#pragma unroll
        for (int p = 0; p < 4; p++) {
            const int jl = vr + 8 * p;
            *(float4*)&bls[jl][vc] =
                *(const float4*)&Vw[(size_t)(row0 + j0 + jl) * DV + dv0 + vc];
        }
        __syncthreads();
#pragma unroll
        for (int jr = 0; jr < 32; jr++) {
            float af[8], bf[8];
            *(float4*)&af[0] = *(const float4*)&scT[jr][ty * 8];
            *(float4*)&af[4] = *(const float4*)&scT[jr][ty * 8 + 4];
            *(float4*)&bf[0] = *(const float4*)&bls[jr][tx * 8];
            *(float4*)&bf[4] = *(const float4*)&bls[jr][tx * 8 + 4];
#pragma unroll
            for (int ii = 0; ii < 8; ii++)
#pragma unroll
                for (int jj = 0; jj < 8; jj++) acc[ii][jj] += af[ii] * bf[jj];
        }
    }

    const size_t sbase = (size_t)(b * NCH + c) * (DH * DV);
    for (int d0 = 0; d0 < DH; d0 += 32) {
        __syncthreads();
#pragma unroll
        for (int p = 0; p < 4; p++) {
            const int i = ir + 32 * p;
            const float g = exp2f((float)i * LOG2_GAMMA);
            float4 q = *(const float4*)&Qw[(size_t)(row0 + i) * DH + d0 + dg];
            qT[dg + 0][i] = q.x * g; qT[dg + 1][i] = q.y * g;
            qT[dg + 2][i] = q.z * g; qT[dg + 3][i] = q.w * g;
        }
#pragma unroll
        for (int p = 0; p < 4; p++) {
            const int dr = vr + 8 * p;
            *(float4*)&bls[dr][vc] =
                *(const float4*)&Sw[sbase + (size_t)(d0 + dr) * DV + dv0 + vc];
        }
        __syncthreads();
#pragma unroll
        for (int dd = 0; dd < 32; dd++) {
            float af[8], bf[8];
            *(float4*)&af[0] = *(const float4*)&qT[dd][ty * 8];
            *(float4*)&af[4] = *(const float4*)&qT[dd][ty * 8 + 4];
            *(float4*)&bf[0] = *(const float4*)&bls[dd][tx * 8];
            *(float4*)&bf[4] = *(const float4*)&bls[dd][tx * 8 + 4];
#pragma unroll
            for (int ii = 0; ii < 8; ii++)
#pragma unroll
                for (int jj = 0; jj < 8; jj++) acc[ii][jj] += af[ii] * bf[jj];
        }
    }

#pragma unroll
    for (int ii = 0; ii < 8; ii++) {
        const int i = ty * 8 + ii;
        float* dst = &out[(size_t)(row0 + i) * DV + dv0 + tx * 8];
        *(float4*)&dst[0] = make_float4(acc[ii][0], acc[ii][1], acc[ii][2], acc[ii][3]);
        *(float4*)&dst[4] = make_float4(acc[ii][4], acc[ii][5], acc[ii][6], acc[ii][7]);
    }
}

// ---------------------------------------------------------------------------
extern "C" void kernel_launch(void* const* d_in, const int* in_sizes, int n_in,
                              void* d_out, int out_size, void* d_ws, size_t ws_size,
                              hipStream_t stream) {
    const float* X  = (const float*)d_in[0];
    const float* WQ = (const float*)d_in[1];
    const float* WK = (const float*)d_in[2];
    const float* WV = (const float*)d_in[3];
    float* out = (float*)d_out;

    // Workspace (floats unless noted):
    //   Qw 4.19M | Kw 4.19M | Vw 8.39M | Uw 16.78M floats (67.1 MB)
    //   Xhi/Xlo bf16 (67.1 MB each) OVERLAP Uw region (used only before chunk_kv)
    //   Bhi/Blo bf16 (4.2 MB each) after Xlo.  Total ~210 MB.
    float* ws = (float*)d_ws;
    float* Qw = ws;
    float* Kw = Qw + (size_t)NB * SEQ * DH;
    float* Vw = Kw + (size_t)NB * SEQ * DH;
    float* Uw = Vw + (size_t)NB * SEQ * DV;
    unsigned short* Xhi = (unsigned short*)Uw;
    unsigned short* Xlo = Xhi + (size_t)NB * SEQ * HID;
    unsigned short* Bhi = Xlo + (size_t)NB * SEQ * HID;
    unsigned short* Blo = Bhi + (size_t)HID * NQKV;

    xcvt_kernel<<<(NB * SEQ * HID / 4) / 256, 256, 0, stream>>>(X, Xhi, Xlo);
    wcvt_kernel<<<512, 256, 0, stream>>>(WQ, WK, WV, Bhi, Blo);
    qkv_mfma_kernel<<<1024, 256, 0, stream>>>(Xhi, Xlo, Bhi, Blo, Qw, Kw, Vw);
    chunk_kv_kernel<<<1024, 256, 0, stream>>>(Kw, Vw, Uw);
    scan_kernel<<<2048, 256, 0, stream>>>(Uw);
    out_kernel<<<512, 256, 0, stream>>>(Qw, Kw, Vw, Uw, out);
}

// Round 3
// 1395.176 us; speedup vs baseline: 1.5535x; 1.0541x over previous
//
#include <hip/hip_runtime.h>
#include <math.h>

#define NB 4
#define SEQ 4096
#define HID 2048
#define DH 256
#define DV 512
#define NQKV 1024               // DH + DH + DV packed
#define CHUNK 128
#define NCH 32                  // SEQ/CHUNK
// log2(0.96875)
#define LOG2_GAMMA (-0.045803689613124794f)
// log2(10000)
#define LOG2_10000 13.287712379549449f

typedef __attribute__((ext_vector_type(8))) short short8;
typedef __attribute__((ext_vector_type(4))) float floatx4;

// ---------------------------------------------------------------------------
// helpers
// ---------------------------------------------------------------------------
__device__ __forceinline__ unsigned short bf16_rne(float v) {
    unsigned int u = __float_as_uint(v);
    u += 0x7fff + ((u >> 16) & 1);
    return (unsigned short)(u >> 16);
}

// async global->LDS, 16 bytes per lane. LDS dest = wave-uniform base + lane*16.
__device__ __forceinline__ void gld16(const void* g, void* l) {
    __builtin_amdgcn_global_load_lds(
        reinterpret_cast<const __attribute__((address_space(1))) unsigned int*>(
            reinterpret_cast<uintptr_t>(g)),
        reinterpret_cast<__attribute__((address_space(3))) unsigned int*>(
            reinterpret_cast<uintptr_t>(l)),
        16, 0, 0);
}

// ---------------------------------------------------------------------------
// Kernel 0a: X fp32 -> Xhi/Xlo bf16 (split precision), row-major [M][K].
// ---------------------------------------------------------------------------
__global__ __launch_bounds__(256) void xcvt_kernel(
    const float* __restrict__ X, unsigned short* __restrict__ Xhi,
    unsigned short* __restrict__ Xlo)
{
    const int i = blockIdx.x * 256 + threadIdx.x;   // one float4 per thread
    float4 x = ((const float4*)X)[i];
    ushort4 h, l;
    {
        h.x = bf16_rne(x.x); l.x = bf16_rne(x.x - __uint_as_float((unsigned)h.x << 16));
        h.y = bf16_rne(x.y); l.y = bf16_rne(x.y - __uint_as_float((unsigned)h.y << 16));
        h.z = bf16_rne(x.z); l.z = bf16_rne(x.z - __uint_as_float((unsigned)h.z << 16));
        h.w = bf16_rne(x.w); l.w = bf16_rne(x.w - __uint_as_float((unsigned)h.w << 16));
    }
    ((ushort4*)Xhi)[i] = h;
    ((ushort4*)Xlo)[i] = l;
}

// ---------------------------------------------------------------------------
// Kernel 0b: W_Q|W_K|W_V fp32 [K][N-region] -> transposed packed bf16 hi/lo
// Bt[n][k], n in 0..1023 (Q cols 0-255, K 256-511, V 512-1023), k in 0..2047.
// ---------------------------------------------------------------------------
__global__ __launch_bounds__(256) void wcvt_kernel(
    const float* __restrict__ WQ, const float* __restrict__ WK,
    const float* __restrict__ WV, unsigned short* __restrict__ Bhi,
    unsigned short* __restrict__ Blo)
{
    __shared__ unsigned short sh[64][65];
    __shared__ unsigned short sl[64][65];
    const int bid = blockIdx.x;         // 32 k-tiles * 16 n-tiles
    const int kt = bid & 31;
    const int ntile = bid >> 5;
    const int k0 = kt * 64, n0 = ntile * 64;

    const float* W; int ld, nl0;
    if (n0 < 256)      { W = WQ; ld = DH; nl0 = n0; }
    else if (n0 < 512) { W = WK; ld = DH; nl0 = n0 - 256; }
    else               { W = WV; ld = DV; nl0 = n0 - 512; }

    const int t = threadIdx.x;
#pragma unroll
    for (int p = 0; p < 4; p++) {
        const int kl = (t >> 4) + p * 16;
        const int ng = (t & 15) * 4;
        float4 w = *(const float4*)&W[(size_t)(k0 + kl) * ld + nl0 + ng];
        sh[kl][ng + 0] = bf16_rne(w.x);
        sl[kl][ng + 0] = bf16_rne(w.x - __uint_as_float((unsigned)sh[kl][ng + 0] << 16));
        sh[kl][ng + 1] = bf16_rne(w.y);
        sl[kl][ng + 1] = bf16_rne(w.y - __uint_as_float((unsigned)sh[kl][ng + 1] << 16));
        sh[kl][ng + 2] = bf16_rne(w.z);
        sl[kl][ng + 2] = bf16_rne(w.z - __uint_as_float((unsigned)sh[kl][ng + 2] << 16));
        sh[kl][ng + 3] = bf16_rne(w.w);
        sl[kl][ng + 3] = bf16_rne(w.w - __uint_as_float((unsigned)sh[kl][ng + 3] << 16));
    }
    __syncthreads();
#pragma unroll
    for (int p = 0; p < 4; p++) {
        const int nl = (t >> 4) + p * 16;
        const int kg = (t & 15) * 4;
        ushort4 h, l;
        h.x = sh[kg + 0][nl]; h.y = sh[kg + 1][nl];
        h.z = sh[kg + 2][nl]; h.w = sh[kg + 3][nl];
        l.x = sl[kg + 0][nl]; l.y = sl[kg + 1][nl];
        l.z = sl[kg + 2][nl]; l.w = sl[kg + 3][nl];
        *(ushort4*)&Bhi[(size_t)(n0 + nl) * HID + k0 + kg] = h;
        *(ushort4*)&Blo[(size_t)(n0 + nl) * HID + k0 + kg] = l;
    }
}

// ---------------------------------------------------------------------------
// Kernel 1: QKV projection via split-bf16 MFMA + xPos epilogue.
// C = X @ [W_Q|W_K|W_V], M=16384, N=1024, K=2048.
// 128x128 tile, BK=32, 4 waves (each 64x64 = 4x4 MFMA 16x16x32 tiles).
// Split products: ah*bh + al*bh + ah*bl (rel err ~2^-16).
//
// Register discipline (round-3 fix): round-2 spilled 64 dwords/thread/iter
// (WRITE_SIZE 4.2 GB) because all 16 fragments were live at once under a
// ~68-arch-VGPR allocation. Now only A-frags (8 short8 = 32 VGPRs) are
// hoisted; B-frags are loaded one hi/lo pair per j (8 VGPRs live).
// ---------------------------------------------------------------------------
__global__ __launch_bounds__(256, 1) void qkv_mfma_kernel(
    const unsigned short* __restrict__ Xhi, const unsigned short* __restrict__ Xlo,
    const unsigned short* __restrict__ Bhi, const unsigned short* __restrict__ Blo,
    float* __restrict__ Qw, float* __restrict__ Kw, float* __restrict__ Vw)
{
    __shared__ unsigned short Ah[128 * 32];
    __shared__ unsigned short Al[128 * 32];
    __shared__ unsigned short Bh[128 * 32];
    __shared__ unsigned short Bl[128 * 32];

    // XCD swizzle: hardware round-robins consecutive blocks over 8 XCDs.
    // Map so the 8 n-tiles of one m-tile share bid&7 (same XCD) and are
    // dispatched consecutively there -> A-tile fetched ~once per XCD epoch.
    const int bid = blockIdx.x;          // 1024 blocks
    const int xcd = bid & 7;
    const int nt  = (bid >> 3) & 7;      // 8 n-tiles
    const int mt  = (xcd << 4) | (bid >> 6);   // 128 m-tiles
    const int m0 = mt * 128, n0 = nt * 128;

    const int t = threadIdx.x;
    const int w = t >> 6, lane = t & 63;

    floatx4 acc[4][4];
#pragma unroll
    for (int i = 0; i < 4; i++)
#pragma unroll
        for (int j = 0; j < 4; j++) acc[i][j] = (floatx4)0.0f;

    // staging source addresses (elements). lane i -> row i/4, cols (i%4)*8..+8
    const size_t aoff = (size_t)(m0 + w * 16 + (lane >> 2)) * HID + (lane & 3) * 8;
    const size_t boff = (size_t)(n0 + w * 16 + (lane >> 2)) * HID + (lane & 3) * 8;
    unsigned short* const ldsA0 = &Ah[(w * 16) * 32];
    unsigned short* const ldsA1 = &Ah[(64 + w * 16) * 32];
    unsigned short* const ldsAl0 = &Al[(w * 16) * 32];
    unsigned short* const ldsAl1 = &Al[(64 + w * 16) * 32];
    unsigned short* const ldsB0 = &Bh[(w * 16) * 32];
    unsigned short* const ldsB1 = &Bh[(64 + w * 16) * 32];
    unsigned short* const ldsBl0 = &Bl[(w * 16) * 32];
    unsigned short* const ldsBl1 = &Bl[(64 + w * 16) * 32];

    const int wm = (w & 1) << 6, wn = (w >> 1) << 6;
    const int fr = lane & 15, fq = (lane >> 4) * 8;

    for (int k0 = 0; k0 < HID; k0 += 32) {
        __syncthreads();   // prior iteration's LDS reads done
        gld16(Xhi + aoff + k0, ldsA0);
        gld16(Xhi + aoff + 64 * HID + k0, ldsA1);
        gld16(Xlo + aoff + k0, ldsAl0);
        gld16(Xlo + aoff + 64 * HID + k0, ldsAl1);
        gld16(Bhi + boff + k0, ldsB0);
        gld16(Bhi + boff + 64 * HID + k0, ldsB1);
        gld16(Blo + boff + k0, ldsBl0);
        gld16(Blo + boff + 64 * HID + k0, ldsBl1);
        __syncthreads();   // compiler drains vmcnt(0) before barrier

        // hoist A fragments only (32 VGPRs)
        short8 ah[4], al[4];
#pragma unroll
        for (int i = 0; i < 4; i++) {
            const int ra = (wm + i * 16 + fr) * 32 + fq;
            ah[i] = *(const short8*)&Ah[ra];
            al[i] = *(const short8*)&Al[ra];
        }
        // one B hi/lo pair live at a time
#pragma unroll
        for (int j = 0; j < 4; j++) {
            const int rb = (wn + j * 16 + fr) * 32 + fq;
            {
                const short8 bh = *(const short8*)&Bh[rb];
#pragma unroll
                for (int i = 0; i < 4; i++) {
                    acc[i][j] = __builtin_amdgcn_mfma_f32_16x16x32_bf16(ah[i], bh, acc[i][j], 0, 0, 0);
                    acc[i][j] = __builtin_amdgcn_mfma_f32_16x16x32_bf16(al[i], bh, acc[i][j], 0, 0, 0);
                }
            }
            {
                const short8 bl = *(const short8*)&Bl[rb];
#pragma unroll
                for (int i = 0; i < 4; i++)
                    acc[i][j] = __builtin_amdgcn_mfma_f32_16x16x32_bf16(ah[i], bl, acc[i][j], 0, 0, 0);
            }
        }
    }

    // epilogue. C/D layout: col = lane&15, row = (lane>>4)*4 + reg.
    const int cl = lane & 15, rq = (lane >> 4) << 2;
    if (n0 >= 512) {
        const int c0v = n0 - 512 + wn;
#pragma unroll
        for (int i = 0; i < 4; i++)
#pragma unroll
            for (int j = 0; j < 4; j++) {
                const int c = c0v + j * 16 + cl;
#pragma unroll
                for (int r = 0; r < 4; r++) {
                    const int m = m0 + wm + i * 16 + rq + r;
                    Vw[(size_t)m * DV + c] = acc[i][j][r];
                }
            }
    } else {
        float* dst = (n0 < 256) ? Qw : Kw;
        const float sgn = (n0 < 256) ? 1.f : -1.f;     // K downscaled
        const int nb = (n0 < 256) ? n0 : n0 - 256;
#pragma unroll
        for (int j = 0; j < 4; j++) {
            const int c = nb + wn + j * 16 + cl;
            const float jj = (float)(c >> 1);
            const float sv = (2.f * jj + 0.4f * 256.f) * (1.f / (1.4f * 256.f));
            const float l2sv = log2f(sv) * sgn * (1.f / 512.f);
            const float invf = exp2f(jj * (-LOG2_10000 / 128.f));
            const bool odd = (c & 1) != 0;
#pragma unroll
            for (int i = 0; i < 4; i++) {
#pragma unroll
                for (int r = 0; r < 4; r++) {
                    const int m = m0 + wm + i * 16 + rq + r;
                    const float s = (float)(m & (SEQ - 1));
                    const float x = acc[i][j][r];
                    const float p = __shfl_xor(x, 1, 64);   // rotation partner (c^1)
                    const float sc = exp2f(s * l2sv);
                    const float ang = s * invf;
                    const float sn = sinf(ang), cs = cosf(ang);
                    dst[(size_t)m * DH + c] = odd ? sc * (x * cs + p * sn)
                                                  : sc * (x * cs - p * sn);
                }
            }
        }
    }
}

// ---------------------------------------------------------------------------
// Kernel 2: per-chunk U_c = K^T diag(gamma^(C-i)) V   (256x512 per (b,c)).
// ---------------------------------------------------------------------------
__global__ __launch_bounds__(256, 1) void chunk_kv_kernel(
    const float* __restrict__ Kw, const float* __restrict__ Vw,
    float* __restrict__ Uw)
{
    __shared__ float kls[32][132];
    __shared__ float vls[32][132];

    const int bid = blockIdx.x;      // 1024
    const int vq = bid & 3;
    const int ht = (bid >> 2) & 1;
    const int c  = (bid >> 3) & 31;
    const int b  = bid >> 8;
    const int dh0 = ht * 128, dv0 = vq * 128;
    const int t = threadIdx.x, tx = t & 15, ty = t >> 4;

    float acc[8][8];
#pragma unroll
    for (int i = 0; i < 8; i++)
#pragma unroll
        for (int j = 0; j < 8; j++) acc[i][j] = 0.f;

    const int lr = t >> 5;
    const int lc = (t & 31) << 2;

    for (int i0 = 0; i0 < CHUNK; i0 += 32) {
        __syncthreads();
#pragma unroll
        for (int p = 0; p < 4; p++) {
            const int il = lr + 8 * p;
            const int i = i0 + il;
            const int row = b * SEQ + c * CHUNK + i;
            const float wgt = exp2f((float)(CHUNK - i) * LOG2_GAMMA);
            float4 kv = *(const float4*)&Kw[(size_t)row * DH + dh0 + lc];
            kv.x *= wgt; kv.y *= wgt; kv.z *= wgt; kv.w *= wgt;
            *(float4*)&kls[il][lc] = kv;
            *(float4*)&vls[il][lc] = *(const float4*)&Vw[(size_t)row * DV + dv0 + lc];
        }
        __syncthreads();
#pragma unroll
        for (int i = 0; i < 32; i++) {
            float af[8], bf[8];
            *(float4*)&af[0] = *(const float4*)&kls[i][ty * 8];
            *(float4*)&af[4] = *(const float4*)&kls[i][ty * 8 + 4];
            *(float4*)&bf[0] = *(const float4*)&vls[i][tx * 8];
            *(float4*)&bf[4] = *(const float4*)&vls[i][tx * 8 + 4];
#pragma unroll
            for (int ii = 0; ii < 8; ii++)
#pragma unroll
                for (int jj = 0; jj < 8; jj++) acc[ii][jj] += af[ii] * bf[jj];
        }
    }

    const size_t ub = ((size_t)(b * NCH + c) * DH + dh0 + ty * 8) * DV + dv0 + tx * 8;
#pragma unroll
    for (int ii = 0; ii < 8; ii++) {
        *(float4*)&Uw[ub + (size_t)ii * DV] =
            make_float4(acc[ii][0], acc[ii][1], acc[ii][2], acc[ii][3]);
        *(float4*)&Uw[ub + (size_t)ii * DV + 4] =
            make_float4(acc[ii][4], acc[ii][5], acc[ii][6], acc[ii][7]);
    }
}

// ---------------------------------------------------------------------------
// Kernel 3: exclusive scan over chunks: U[c] <- S_c (state BEFORE chunk c).
// ---------------------------------------------------------------------------
__global__ __launch_bounds__(256) void scan_kernel(float* __restrict__ Uw)
{
    const int t = blockIdx.x * 256 + threadIdx.x;   // 0..524287
    const int b = t >> 17;                          // DH*DV = 131072
    const int r = t & 131071;
    const float gC = exp2f((float)CHUNK * LOG2_GAMMA);
    float s = 0.f;
    const size_t base = (size_t)b * NCH * 131072 + r;
    for (int c = 0; c < NCH; c++) {
        const size_t off = base + (size_t)c * 131072;
        const float u = Uw[off];
        Uw[off] = s;
        s = gC * s + u;
    }
}

// ---------------------------------------------------------------------------
// Kernel 4: O = intra(tril(QK^T) .* gamma^(i-j)) @ V + gamma^i * Q @ S_c.
// ---------------------------------------------------------------------------
__global__ __launch_bounds__(256, 1) void out_kernel(
    const float* __restrict__ Qw, const float* __restrict__ Kw,
    const float* __restrict__ Vw, const float* __restrict__ Sw,
    float* __restrict__ out)
{
    __shared__ float qT[32][132];
    __shared__ float kT[32][36];
    __shared__ float scT[32][132];
    __shared__ float bls[32][132];

    const int bid = blockIdx.x;      // 512
    const int vq = bid & 3;
    const int c  = (bid >> 2) & 31;
    const int b  = bid >> 7;
    const int dv0 = vq * 128;
    const int row0 = b * SEQ + c * CHUNK;
    const int t = threadIdx.x, tx = t & 15, ty = t >> 4;

    float acc[8][8];
#pragma unroll
    for (int i = 0; i < 8; i++)
#pragma unroll
        for (int j = 0; j < 8; j++) acc[i][j] = 0.f;

    const int ir = t >> 3;
    const int dg = (t & 7) << 2;
    const int vr = t >> 5;
    const int vc = (t & 31) << 2;

    for (int j0 = 0; j0 < CHUNK; j0 += 32) {
        float accs[8][2];
#pragma unroll
        for (int ii = 0; ii < 8; ii++) { accs[ii][0] = 0.f; accs[ii][1] = 0.f; }

        for (int d0 = 0; d0 < DH; d0 += 32) {
            __syncthreads();
#pragma unroll
            for (int p = 0; p < 4; p++) {
                const int i = ir + 32 * p;
                float4 q = *(const float4*)&Qw[(size_t)(row0 + i) * DH + d0 + dg];
                qT[dg + 0][i] = q.x; qT[dg + 1][i] = q.y;
                qT[dg + 2][i] = q.z; qT[dg + 3][i] = q.w;
            }
            {
                float4 kv = *(const float4*)&Kw[(size_t)(row0 + j0 + ir) * DH + d0 + dg];
                kT[dg + 0][ir] = kv.x; kT[dg + 1][ir] = kv.y;
                kT[dg + 2][ir] = kv.z; kT[dg + 3][ir] = kv.w;
            }
            __syncthreads();
#pragma unroll
            for (int dd = 0; dd < 32; dd++) {
                float af[8];
                *(float4*)&af[0] = *(const float4*)&qT[dd][ty * 8];
                *(float4*)&af[4] = *(const float4*)&qT[dd][ty * 8 + 4];
                const float b0 = kT[dd][tx * 2], b1 = kT[dd][tx * 2 + 1];
#pragma unroll
                for (int ii = 0; ii < 8; ii++) {
                    accs[ii][0] += af[ii] * b0;
                    accs[ii][1] += af[ii] * b1;
                }
            }
        }
        __syncthreads();
#pragma unroll
        for (int jj = 0; jj < 2; jj++) {
            const int j = j0 + tx * 2 + jj;
#pragma unroll
            for (int ii = 0; ii < 8; ii++) {
                const int i = ty * 8 + ii;
                const int diff = i - j;
                scT[tx * 2 + jj][i] =
                    (diff >= 0) ? accs[ii][jj] * exp2f((float)diff * LOG2_GAMMA) : 0.f;
            }
        }
#pragma unroll
        for (int p = 0; p < 4; p++) {
            const int jl = vr + 8 * p;
            *(float4*)&bls[jl][vc] =
                *(const float4*)&Vw[(size_t)(row0 + j0 + jl) * DV + dv0 + vc];
        }
        __syncthreads();
#pragma unroll
        for (int jr = 0; jr < 32; jr++) {
            float af[8], bf[8];
            *(float4*)&af[0] = *(const float4*)&scT[jr][ty * 8];
            *(float4*)&af[4] = *(const float4*)&scT[jr][ty * 8 + 4];
            *(float4*)&bf[0] = *(const float4*)&bls[jr][tx * 8];
            *(float4*)&bf[4] = *(const float4*)&bls[jr][tx * 8 + 4];
#pragma unroll
            for (int ii = 0; ii < 8; ii++)
#pragma unroll
                for (int jj = 0; jj < 8; jj++) acc[ii][jj] += af[ii] * bf[jj];
        }
    }

    const size_t sbase = (size_t)(b * NCH + c) * (DH * DV);
    for (int d0 = 0; d0 < DH; d0 += 32) {
        __syncthreads();
#pragma unroll
        for (int p = 0; p < 4; p++) {
            const int i = ir + 32 * p;
            const float g = exp2f((float)i * LOG2_GAMMA);
            float4 q = *(const float4*)&Qw[(size_t)(row0 + i) * DH + d0 + dg];
            qT[dg + 0][i] = q.x * g; qT[dg + 1][i] = q.y * g;
            qT[dg + 2][i] = q.z * g; qT[dg + 3][i] = q.w * g;
        }
#pragma unroll
        for (int p = 0; p < 4; p++) {
            const int dr = vr + 8 * p;
            *(float4*)&bls[dr][vc] =
                *(const float4*)&Sw[sbase + (size_t)(d0 + dr) * DV + dv0 + vc];
        }
        __syncthreads();
#pragma unroll
        for (int dd = 0; dd < 32; dd++) {
            float af[8], bf[8];
            *(float4*)&af[0] = *(const float4*)&qT[dd][ty * 8];
            *(float4*)&af[4] = *(const float4*)&qT[dd][ty * 8 + 4];
            *(float4*)&bf[0] = *(const float4*)&bls[dd][tx * 8];
            *(float4*)&bf[4] = *(const float4*)&bls[dd][tx * 8 + 4];
#pragma unroll
            for (int ii = 0; ii < 8; ii++)
#pragma unroll
                for (int jj = 0; jj < 8; jj++) acc[ii][jj] += af[ii] * bf[jj];
        }
    }

#pragma unroll
    for (int ii = 0; ii < 8; ii++) {
        const int i = ty * 8 + ii;
        float* dst = &out[(size_t)(row0 + i) * DV + dv0 + tx * 8];
        *(float4*)&dst[0] = make_float4(acc[ii][0], acc[ii][1], acc[ii][2], acc[ii][3]);
        *(float4*)&dst[4] = make_float4(acc[ii][4], acc[ii][5], acc[ii][6], acc[ii][7]);
    }
}

// ---------------------------------------------------------------------------
extern "C" void kernel_launch(void* const* d_in, const int* in_sizes, int n_in,
                              void* d_out, int out_size, void* d_ws, size_t ws_size,
                              hipStream_t stream) {
    const float* X  = (const float*)d_in[0];
    const float* WQ = (const float*)d_in[1];
    const float* WK = (const float*)d_in[2];
    const float* WV = (const float*)d_in[3];
    float* out = (float*)d_out;

    // Workspace (floats unless noted):
    //   Qw 4.19M | Kw 4.19M | Vw 8.39M | Uw 16.78M floats (67.1 MB)
    //   Xhi/Xlo bf16 (67.1 MB each) OVERLAP Uw region (used only before chunk_kv)
    //   Bhi/Blo bf16 (4.2 MB each) after Xlo.  Total ~210 MB.
    float* ws = (float*)d_ws;
    float* Qw = ws;
    float* Kw = Qw + (size_t)NB * SEQ * DH;
    float* Vw = Kw + (size_t)NB * SEQ * DH;
    float* Uw = Vw + (size_t)NB * SEQ * DV;
    unsigned short* Xhi = (unsigned short*)Uw;
    unsigned short* Xlo = Xhi + (size_t)NB * SEQ * HID;
    unsigned short* Bhi = Xlo + (size_t)NB * SEQ * HID;
    unsigned short* Blo = Bhi + (size_t)HID * NQKV;

    xcvt_kernel<<<(NB * SEQ * HID / 4) / 256, 256, 0, stream>>>(X, Xhi, Xlo);
    wcvt_kernel<<<512, 256, 0, stream>>>(WQ, WK, WV, Bhi, Blo);
    qkv_mfma_kernel<<<1024, 256, 0, stream>>>(Xhi, Xlo, Bhi, Blo, Qw, Kw, Vw);
    chunk_kv_kernel<<<1024, 256, 0, stream>>>(Kw, Vw, Uw);
    scan_kernel<<<2048, 256, 0, stream>>>(Uw);
    out_kernel<<<512, 256, 0, stream>>>(Qw, Kw, Vw, Uw, out);
}

// Round 4
// 1326.937 us; speedup vs baseline: 1.6334x; 1.0514x over previous
//
#include <hip/hip_runtime.h>
#include <math.h>

#define NB 4
#define SEQ 4096
#define HID 2048
#define DH 256
#define DV 512
#define NQKV 1024               // DH + DH + DV packed
#define CHUNK 128
#define NCH 32                  // SEQ/CHUNK
#define MROWS (NB * SEQ)        // 16384
// log2(0.96875)
#define LOG2_GAMMA (-0.045803689613124794f)
// log2(10000)
#define LOG2_10000 13.287712379549449f

typedef __attribute__((ext_vector_type(8))) short short8;
typedef __attribute__((ext_vector_type(4))) float floatx4;

// ---------------------------------------------------------------------------
// helpers
// ---------------------------------------------------------------------------
__device__ __forceinline__ unsigned short bf16_rne(float v) {
    unsigned int u = __float_as_uint(v);
    u += 0x7fff + ((u >> 16) & 1);
    return (unsigned short)(u >> 16);
}
__device__ __forceinline__ float b2f(unsigned short h) {
    return __uint_as_float((unsigned int)h << 16);
}

// async global->LDS, 16 bytes per lane. LDS dest = wave-uniform base + lane*16.
__device__ __forceinline__ void gld16(const void* g, void* l) {
    __builtin_amdgcn_global_load_lds(
        reinterpret_cast<const __attribute__((address_space(1))) unsigned int*>(
            reinterpret_cast<uintptr_t>(g)),
        reinterpret_cast<__attribute__((address_space(3))) unsigned int*>(
            reinterpret_cast<uintptr_t>(l)),
        16, 0, 0);
}

// ---------------------------------------------------------------------------
// Kernel 0a: X fp32 -> bf16 row-major [M][K]. (pure bf16 now: no lo part)
// ---------------------------------------------------------------------------
__global__ __launch_bounds__(256) void xcvt_kernel(
    const float* __restrict__ X, unsigned short* __restrict__ Xb)
{
    const int i = blockIdx.x * 256 + threadIdx.x;   // one float4 per thread
    float4 x = ((const float4*)X)[i];
    ushort4 h;
    h.x = bf16_rne(x.x); h.y = bf16_rne(x.y);
    h.z = bf16_rne(x.z); h.w = bf16_rne(x.w);
    ((ushort4*)Xb)[i] = h;
}

// ---------------------------------------------------------------------------
// Kernel 0b: W_Q|W_K|W_V fp32 [K][Nregion] -> transposed packed bf16 Bt[n][k].
// ---------------------------------------------------------------------------
__global__ __launch_bounds__(256) void wcvt_kernel(
    const float* __restrict__ WQ, const float* __restrict__ WK,
    const float* __restrict__ WV, unsigned short* __restrict__ Bt)
{
    __shared__ unsigned short sh[64][65];
    const int bid = blockIdx.x;         // 32 k-tiles * 16 n-tiles
    const int kt = bid & 31;
    const int ntile = bid >> 5;
    const int k0 = kt * 64, n0 = ntile * 64;

    const float* W; int ld, nl0;
    if (n0 < 256)      { W = WQ; ld = DH; nl0 = n0; }
    else if (n0 < 512) { W = WK; ld = DH; nl0 = n0 - 256; }
    else               { W = WV; ld = DV; nl0 = n0 - 512; }

    const int t = threadIdx.x;
#pragma unroll
    for (int p = 0; p < 4; p++) {
        const int kl = (t >> 4) + p * 16;
        const int ng = (t & 15) * 4;
        float4 w = *(const float4*)&W[(size_t)(k0 + kl) * ld + nl0 + ng];
        sh[kl][ng + 0] = bf16_rne(w.x);
        sh[kl][ng + 1] = bf16_rne(w.y);
        sh[kl][ng + 2] = bf16_rne(w.z);
        sh[kl][ng + 3] = bf16_rne(w.w);
    }
    __syncthreads();
#pragma unroll
    for (int p = 0; p < 4; p++) {
        const int nl = (t >> 4) + p * 16;
        const int kg = (t & 15) * 4;
        ushort4 h;
        h.x = sh[kg + 0][nl]; h.y = sh[kg + 1][nl];
        h.z = sh[kg + 2][nl]; h.w = sh[kg + 3][nl];
        *(ushort4*)&Bt[(size_t)(n0 + nl) * HID + k0 + kg] = h;
    }
}

// ---------------------------------------------------------------------------
// Kernel 1: QKV projection, pure bf16 MFMA + xPos epilogue.
// C = X @ [W_Q|W_K|W_V], M=16384, N=1024, K=2048. 128x128 tile, BK=32.
// Outputs (all bf16): Qb[m][256], Kb[m][256] (xPos'd), Vb[m][512],
// Vt[dv][16384] (transposed copy for the PV MFMA).
// Live fragments: ah[4]+bh[4] = 32 VGPRs -> fits the allocator's ~80 cap,
// no scratch spill (rounds 2/3 spilled 4 GB with the 64-VGPR hi/lo set).
// ---------------------------------------------------------------------------
__global__ __launch_bounds__(256, 1) void qkv_mfma_kernel(
    const unsigned short* __restrict__ Xb, const unsigned short* __restrict__ Bt,
    unsigned short* __restrict__ Qb, unsigned short* __restrict__ Kb,
    unsigned short* __restrict__ Vb, unsigned short* __restrict__ Vt)
{
    __shared__ unsigned short Ah[128 * 32];
    __shared__ unsigned short Bh[128 * 32];

    // XCD swizzle: 8 n-tiles of one m-tile share bid&7 -> same XCD L2.
    const int bid = blockIdx.x;          // 1024 blocks
    const int xcd = bid & 7;
    const int nt  = (bid >> 3) & 7;      // 8 n-tiles
    const int mt  = (xcd << 4) | (bid >> 6);   // 128 m-tiles
    const int m0 = mt * 128, n0 = nt * 128;

    const int t = threadIdx.x;
    const int w = t >> 6, lane = t & 63;

    floatx4 acc[4][4];
#pragma unroll
    for (int i = 0; i < 4; i++)
#pragma unroll
        for (int j = 0; j < 4; j++) acc[i][j] = (floatx4)0.0f;

    const int srow = lane >> 2, scol = (lane & 3) * 8;
    const size_t aoff = (size_t)(m0 + w * 16 + srow) * HID + scol;
    const size_t boff = (size_t)(n0 + w * 16 + srow) * HID + scol;
    unsigned short* const ldsA0 = &Ah[(w * 16) * 32];
    unsigned short* const ldsA1 = &Ah[(64 + w * 16) * 32];
    unsigned short* const ldsB0 = &Bh[(w * 16) * 32];
    unsigned short* const ldsB1 = &Bh[(64 + w * 16) * 32];

    const int wm = (w & 1) << 6, wn = (w >> 1) << 6;
    const int fr = lane & 15, fq = (lane >> 4) * 8;

    for (int k0 = 0; k0 < HID; k0 += 32) {
        __syncthreads();
        gld16(Xb + aoff + k0, ldsA0);
        gld16(Xb + aoff + 64 * HID + k0, ldsA1);
        gld16(Bt + boff + k0, ldsB0);
        gld16(Bt + boff + 64 * HID + k0, ldsB1);
        __syncthreads();

        short8 ah[4], bh[4];
#pragma unroll
        for (int i = 0; i < 4; i++) {
            ah[i] = *(const short8*)&Ah[(wm + i * 16 + fr) * 32 + fq];
            bh[i] = *(const short8*)&Bh[(wn + i * 16 + fr) * 32 + fq];
        }
#pragma unroll
        for (int i = 0; i < 4; i++)
#pragma unroll
            for (int j = 0; j < 4; j++)
                acc[i][j] = __builtin_amdgcn_mfma_f32_16x16x32_bf16(ah[i], bh[j], acc[i][j], 0, 0, 0);
    }

    // epilogue. C/D layout: col = lane&15, row = (lane>>4)*4 + reg.
    const int cl = lane & 15, rq = (lane >> 4) << 2;
    if (n0 >= 512) {
#pragma unroll
        for (int i = 0; i < 4; i++)
#pragma unroll
            for (int j = 0; j < 4; j++) {
                const int c = n0 - 512 + wn + j * 16 + cl;   // dv 0..511
#pragma unroll
                for (int r = 0; r < 4; r++) {
                    const int m = m0 + wm + i * 16 + rq + r;
                    const unsigned short hv = bf16_rne(acc[i][j][r]);
                    Vb[(size_t)m * DV + c] = hv;
                    Vt[(size_t)c * MROWS + m] = hv;
                }
            }
    } else {
        unsigned short* dst = (n0 < 256) ? Qb : Kb;
        const float sgn = (n0 < 256) ? 1.f : -1.f;     // K downscaled
        const int nb = (n0 < 256) ? n0 : n0 - 256;
#pragma unroll
        for (int j = 0; j < 4; j++) {
            const int c = nb + wn + j * 16 + cl;
            const float jj = (float)(c >> 1);
            const float sv = (2.f * jj + 0.4f * 256.f) * (1.f / (1.4f * 256.f));
            const float l2sv = log2f(sv) * sgn * (1.f / 512.f);
            const float invf = exp2f(jj * (-LOG2_10000 / 128.f));
            const bool odd = (c & 1) != 0;
#pragma unroll
            for (int i = 0; i < 4; i++) {
#pragma unroll
                for (int r = 0; r < 4; r++) {
                    const int m = m0 + wm + i * 16 + rq + r;
                    const float s = (float)(m & (SEQ - 1));
                    const float x = acc[i][j][r];
                    const float p = __shfl_xor(x, 1, 64);   // partner col c^1
                    const float sc = exp2f(s * l2sv);
                    const float ang = s * invf;
                    const float sn = sinf(ang), cs = cosf(ang);
                    const float o = odd ? sc * (x * cs + p * sn)
                                        : sc * (x * cs - p * sn);
                    dst[(size_t)m * DH + c] = bf16_rne(o);
                }
            }
        }
    }
}

// ---------------------------------------------------------------------------
// Kernel 2: per-chunk U_c = K^T diag(gamma^(C-i)) V, written TRANSPOSED:
// Ut[b][c][dv(512)][dh(256)] fp32 (B-operand layout for the cross MFMA).
// fp32 VALU math (only 4.3 GF), bf16 inputs.
// ---------------------------------------------------------------------------
__global__ __launch_bounds__(256, 1) void chunk_kv_kernel(
    const unsigned short* __restrict__ Kb, const unsigned short* __restrict__ Vb,
    float* __restrict__ Ut)
{
    __shared__ float kls[32][132];   // [i][dh], pre-scaled by gamma^(C-i)
    __shared__ float vls[32][132];   // [i][dv]

    const int bid = blockIdx.x;      // 1024
    const int vq = bid & 3;
    const int ht = (bid >> 2) & 1;
    const int c  = (bid >> 3) & 31;
    const int b  = bid >> 8;
    const int dh0 = ht * 128, dv0 = vq * 128;
    const int t = threadIdx.x, tx = t & 15, ty = t >> 4;

    float acc[8][8];
#pragma unroll
    for (int i = 0; i < 8; i++)
#pragma unroll
        for (int j = 0; j < 8; j++) acc[i][j] = 0.f;

    const int lr = t >> 5;
    const int lc = (t & 31) << 2;

    for (int i0 = 0; i0 < CHUNK; i0 += 32) {
        __syncthreads();
#pragma unroll
        for (int p = 0; p < 4; p++) {
            const int il = lr + 8 * p;
            const int i = i0 + il;
            const int row = b * SEQ + c * CHUNK + i;
            const float wgt = exp2f((float)(CHUNK - i) * LOG2_GAMMA);
            ushort4 kq = *(const ushort4*)&Kb[(size_t)row * DH + dh0 + lc];
            kls[il][lc + 0] = b2f(kq.x) * wgt;
            kls[il][lc + 1] = b2f(kq.y) * wgt;
            kls[il][lc + 2] = b2f(kq.z) * wgt;
            kls[il][lc + 3] = b2f(kq.w) * wgt;
            ushort4 vv = *(const ushort4*)&Vb[(size_t)row * DV + dv0 + lc];
            vls[il][lc + 0] = b2f(vv.x);
            vls[il][lc + 1] = b2f(vv.y);
            vls[il][lc + 2] = b2f(vv.z);
            vls[il][lc + 3] = b2f(vv.w);
        }
        __syncthreads();
#pragma unroll
        for (int i = 0; i < 32; i++) {
            float af[8], bf[8];
            *(float4*)&af[0] = *(const float4*)&kls[i][ty * 8];
            *(float4*)&af[4] = *(const float4*)&kls[i][ty * 8 + 4];
            *(float4*)&bf[0] = *(const float4*)&vls[i][tx * 8];
            *(float4*)&bf[4] = *(const float4*)&vls[i][tx * 8 + 4];
#pragma unroll
            for (int ii = 0; ii < 8; ii++)
#pragma unroll
                for (int jj = 0; jj < 8; jj++) acc[ii][jj] += af[ii] * bf[jj];
        }
    }

    // transposed store: Ut[((b*32+c)*512 + dv)*256 + dh]
#pragma unroll
    for (int jj = 0; jj < 8; jj++) {
        const int dv = dv0 + tx * 8 + jj;
        const size_t base = ((size_t)(b * NCH + c) * DV + dv) * DH + dh0 + ty * 8;
        *(float4*)&Ut[base] = make_float4(acc[0][jj], acc[1][jj], acc[2][jj], acc[3][jj]);
        *(float4*)&Ut[base + 4] = make_float4(acc[4][jj], acc[5][jj], acc[6][jj], acc[7][jj]);
    }
}

// ---------------------------------------------------------------------------
// Kernel 3: exclusive scan over chunks: Ut[c] <- S_c (state BEFORE chunk c).
// Layout-agnostic elementwise scan over the 131072 per-(b,c) entries.
// ---------------------------------------------------------------------------
__global__ __launch_bounds__(256) void scan_kernel(float* __restrict__ Ut)
{
    const int t = blockIdx.x * 256 + threadIdx.x;   // 0..524287
    const int b = t >> 17;                          // DV*DH = 131072
    const int r = t & 131071;
    const float gC = exp2f((float)CHUNK * LOG2_GAMMA);
    float s = 0.f;
    const size_t base = (size_t)b * NCH * 131072 + r;
    for (int c = 0; c < NCH; c++) {
        const size_t off = base + (size_t)c * 131072;
        const float u = Ut[off];
        Ut[off] = s;
        s = gC * s + u;
    }
}

// ---------------------------------------------------------------------------
// Kernel 4: O = (tril(QK^T) .* gamma^(i-j)) @ V  +  (gamma^i Q) @ S_c^T.
// Full bf16 MFMA. Block = (b, chunk, dv-quarter), 128(i) x 128(dv) output,
// 4 waves of 64x64.
// Phase 1: P = QK^T (MFMA over dh=256) -> decay mask -> bf16 in LDS (padded).
// Phase 2: acc = P @ Vt-tile (MFMA over j=128).
// Phase 3: acc += (gamma^i Q) @ St-tile (MFMA over dh=256; gamma folded into
//          Q staging, St converted fp32->bf16 in staging).
// ---------------------------------------------------------------------------
__global__ __launch_bounds__(256, 1) void out_mfma_kernel(
    const unsigned short* __restrict__ Qb, const unsigned short* __restrict__ Kb,
    const unsigned short* __restrict__ Vt, const float* __restrict__ St,
    float* __restrict__ out)
{
    __shared__ unsigned short Pa[128 * 136];   // P bf16, row stride 136 (pad)
    __shared__ unsigned short As[128 * 32];
    __shared__ unsigned short Bs[128 * 32];

    const int bid = blockIdx.x;      // 512
    const int vq = bid & 3;
    const int c  = (bid >> 2) & 31;
    const int b  = bid >> 7;
    const int dv0 = vq * 128;
    const int row0 = b * SEQ + c * CHUNK;

    const int t = threadIdx.x;
    const int w = t >> 6, lane = t & 63;
    const int wm = (w & 1) << 6, wn = (w >> 1) << 6;
    const int fr = lane & 15, fq = (lane >> 4) * 8;
    const int cl = lane & 15, rq = (lane >> 4) << 2;
    const int srow = lane >> 2, scol = (lane & 3) * 8;

    floatx4 acc[4][4];
#pragma unroll
    for (int i = 0; i < 4; i++)
#pragma unroll
        for (int j = 0; j < 4; j++) acc[i][j] = (floatx4)0.0f;

    // ---------------- phase 1: P = Q K^T ----------------
    for (int d0 = 0; d0 < DH; d0 += 32) {
        __syncthreads();
        gld16(&Qb[(size_t)(row0 + w * 16 + srow) * DH + d0 + scol], &As[(w * 16) * 32]);
        gld16(&Qb[(size_t)(row0 + 64 + w * 16 + srow) * DH + d0 + scol], &As[(64 + w * 16) * 32]);
        gld16(&Kb[(size_t)(row0 + w * 16 + srow) * DH + d0 + scol], &Bs[(w * 16) * 32]);
        gld16(&Kb[(size_t)(row0 + 64 + w * 16 + srow) * DH + d0 + scol], &Bs[(64 + w * 16) * 32]);
        __syncthreads();
        short8 a[4], bb[4];
#pragma unroll
        for (int i = 0; i < 4; i++) {
            a[i]  = *(const short8*)&As[(wm + i * 16 + fr) * 32 + fq];
            bb[i] = *(const short8*)&Bs[(wn + i * 16 + fr) * 32 + fq];
        }
#pragma unroll
        for (int i = 0; i < 4; i++)
#pragma unroll
            for (int j = 0; j < 4; j++)
                acc[i][j] = __builtin_amdgcn_mfma_f32_16x16x32_bf16(a[i], bb[j], acc[i][j], 0, 0, 0);
    }

    // decay mask + bf16 -> Pa[i][j] (i = q row in chunk, j = k row)
#pragma unroll
    for (int i = 0; i < 4; i++)
#pragma unroll
        for (int j = 0; j < 4; j++) {
            const int jj = wn + j * 16 + cl;
#pragma unroll
            for (int r = 0; r < 4; r++) {
                const int ii = wm + i * 16 + rq + r;
                const int diff = ii - jj;
                const float v = (diff >= 0) ? acc[i][j][r] * exp2f((float)diff * LOG2_GAMMA) : 0.f;
                Pa[ii * 136 + jj] = bf16_rne(v);
            }
            acc[i][j] = (floatx4)0.0f;     // reset for O accumulation
        }
    __syncthreads();   // Pa visible to all waves; phase-1 LDS reads done

    // ---------------- phase 2: acc = P @ V ----------------
    for (int k0 = 0; k0 < CHUNK; k0 += 32) {
        if (k0) __syncthreads();
        gld16(&Vt[(size_t)(dv0 + w * 16 + srow) * MROWS + row0 + k0 + scol], &Bs[(w * 16) * 32]);
        gld16(&Vt[(size_t)(dv0 + 64 + w * 16 + srow) * MROWS + row0 + k0 + scol], &Bs[(64 + w * 16) * 32]);
        __syncthreads();
        short8 a[4], bb[4];
#pragma unroll
        for (int i = 0; i < 4; i++) {
            a[i]  = *(const short8*)&Pa[(wm + i * 16 + fr) * 136 + k0 + fq];
            bb[i] = *(const short8*)&Bs[(wn + i * 16 + fr) * 32 + fq];
        }
#pragma unroll
        for (int i = 0; i < 4; i++)
#pragma unroll
            for (int j = 0; j < 4; j++)
                acc[i][j] = __builtin_amdgcn_mfma_f32_16x16x32_bf16(a[i], bb[j], acc[i][j], 0, 0, 0);
    }

    // ---------------- phase 3: acc += (gamma^i Q) @ St ----------------
    const size_t stbase = ((size_t)(b * NCH + c) * DV + dv0) * DH;
    const int xr = t >> 3, xc = (t & 7) * 4;     // staging: 32 rows x 4 passes
    for (int d0 = 0; d0 < DH; d0 += 32) {
        __syncthreads();
#pragma unroll
        for (int p = 0; p < 4; p++) {
            const int r = xr + 32 * p;           // i in chunk
            const float g = exp2f((float)r * LOG2_GAMMA);
            ushort4 q = *(const ushort4*)&Qb[(size_t)(row0 + r) * DH + d0 + xc];
            ushort4 h;
            h.x = bf16_rne(b2f(q.x) * g); h.y = bf16_rne(b2f(q.y) * g);
            h.z = bf16_rne(b2f(q.z) * g); h.w = bf16_rne(b2f(q.w) * g);
            *(ushort4*)&As[r * 32 + xc] = h;
        }
#pragma unroll
        for (int p = 0; p < 4; p++) {
            const int r = xr + 32 * p;           // dv row (local)
            float4 s = *(const float4*)&St[stbase + (size_t)r * DH + d0 + xc];
            ushort4 h;
            h.x = bf16_rne(s.x); h.y = bf16_rne(s.y);
            h.z = bf16_rne(s.z); h.w = bf16_rne(s.w);
            *(ushort4*)&Bs[r * 32 + xc] = h;
        }
        __syncthreads();
        short8 a[4], bb[4];
#pragma unroll
        for (int i = 0; i < 4; i++) {
            a[i]  = *(const short8*)&As[(wm + i * 16 + fr) * 32 + fq];
            bb[i] = *(const short8*)&Bs[(wn + i * 16 + fr) * 32 + fq];
        }
#pragma unroll
        for (int i = 0; i < 4; i++)
#pragma unroll
            for (int j = 0; j < 4; j++)
                acc[i][j] = __builtin_amdgcn_mfma_f32_16x16x32_bf16(a[i], bb[j], acc[i][j], 0, 0, 0);
    }

    // epilogue: fp32 store
#pragma unroll
    for (int i = 0; i < 4; i++)
#pragma unroll
        for (int j = 0; j < 4; j++) {
            const int dv = dv0 + wn + j * 16 + cl;
#pragma unroll
            for (int r = 0; r < 4; r++) {
                const int m = row0 + wm + i * 16 + rq + r;
                out[(size_t)m * DV + dv] = acc[i][j][r];
            }
        }
}

// ---------------------------------------------------------------------------
extern "C" void kernel_launch(void* const* d_in, const int* in_sizes, int n_in,
                              void* d_out, int out_size, void* d_ws, size_t ws_size,
                              hipStream_t stream) {
    const float* X  = (const float*)d_in[0];
    const float* WQ = (const float*)d_in[1];
    const float* WK = (const float*)d_in[2];
    const float* WV = (const float*)d_in[3];
    float* out = (float*)d_out;

    // Workspace layout:
    //   Qb 8.4MB | Kb 8.4MB | Vb 16.8MB | Vt 16.8MB | Ut 67.1MB (fp32)
    //   Xb bf16 67.1MB OVERLAPS Ut (Xb dead after qkv; Ut written after)
    //   Bt bf16 4.2MB. Total ~122 MB.
    char* ws = (char*)d_ws;
    unsigned short* Qb = (unsigned short*)ws;
    unsigned short* Kb = Qb + (size_t)MROWS * DH;
    unsigned short* Vb = Kb + (size_t)MROWS * DH;
    unsigned short* Vt = Vb + (size_t)MROWS * DV;
    float*          Ut = (float*)(Vt + (size_t)MROWS * DV);
    unsigned short* Xb = (unsigned short*)Ut;       // overlap
    unsigned short* Bt = (unsigned short*)(Ut + (size_t)NB * NCH * DV * DH);

    xcvt_kernel<<<(MROWS * HID / 4) / 256, 256, 0, stream>>>(X, Xb);
    wcvt_kernel<<<512, 256, 0, stream>>>(WQ, WK, WV, Bt);
    qkv_mfma_kernel<<<1024, 256, 0, stream>>>(Xb, Bt, Qb, Kb, Vb, Vt);
    chunk_kv_kernel<<<1024, 256, 0, stream>>>(Kb, Vb, Ut);
    scan_kernel<<<2048, 256, 0, stream>>>(Ut);
    out_mfma_kernel<<<512, 256, 0, stream>>>(Qb, Kb, Vt, Ut, out);
}

// Round 5
// 414.628 us; speedup vs baseline: 5.2272x; 3.2003x over previous
//
#include <hip/hip_runtime.h>
#include <math.h>

#define NB 4
#define SEQ 4096
#define HID 2048
#define DH 256
#define DV 512
#define NQKV 1024               // DH + DH + DV packed
#define CHUNK 128
#define NCH 32                  // SEQ/CHUNK
#define MROWS (NB * SEQ)        // 16384
// log2(0.96875)
#define LOG2_GAMMA (-0.045803689613124794f)
// log2(10000)
#define LOG2_10000 13.287712379549449f

typedef __attribute__((ext_vector_type(8))) short short8;
typedef __attribute__((ext_vector_type(4))) float floatx4;

// ---------------------------------------------------------------------------
// helpers
// ---------------------------------------------------------------------------
__device__ __forceinline__ unsigned short bf16_rne(float v) {
    unsigned int u = __float_as_uint(v);
    u += 0x7fff + ((u >> 16) & 1);
    return (unsigned short)(u >> 16);
}
__device__ __forceinline__ float b2f(unsigned short h) {
    return __uint_as_float((unsigned int)h << 16);
}

// async global->LDS, 16 bytes per lane. LDS dest = wave-uniform base + lane*16.
__device__ __forceinline__ void gld16(const void* g, void* l) {
    __builtin_amdgcn_global_load_lds(
        reinterpret_cast<const __attribute__((address_space(1))) unsigned int*>(
            reinterpret_cast<uintptr_t>(g)),
        reinterpret_cast<__attribute__((address_space(3))) unsigned int*>(
            reinterpret_cast<uintptr_t>(l)),
        16, 0, 0);
}

// ---------------------------------------------------------------------------
// Kernel 0a: X fp32 -> bf16 row-major [M][K].
// ---------------------------------------------------------------------------
__global__ __launch_bounds__(256) void xcvt_kernel(
    const float* __restrict__ X, unsigned short* __restrict__ Xb)
{
    const int i = blockIdx.x * 256 + threadIdx.x;   // one float4 per thread
    float4 x = ((const float4*)X)[i];
    ushort4 h;
    h.x = bf16_rne(x.x); h.y = bf16_rne(x.y);
    h.z = bf16_rne(x.z); h.w = bf16_rne(x.w);
    ((ushort4*)Xb)[i] = h;
}

// ---------------------------------------------------------------------------
// Kernel 0b: W_Q|W_K|W_V fp32 [K][Nregion] -> transposed packed bf16 Bt[n][k].
// ---------------------------------------------------------------------------
__global__ __launch_bounds__(256) void wcvt_kernel(
    const float* __restrict__ WQ, const float* __restrict__ WK,
    const float* __restrict__ WV, unsigned short* __restrict__ Bt)
{
    __shared__ unsigned short sh[64][65];
    const int bid = blockIdx.x;         // 32 k-tiles * 16 n-tiles
    const int kt = bid & 31;
    const int ntile = bid >> 5;
    const int k0 = kt * 64, n0 = ntile * 64;

    const float* W; int ld, nl0;
    if (n0 < 256)      { W = WQ; ld = DH; nl0 = n0; }
    else if (n0 < 512) { W = WK; ld = DH; nl0 = n0 - 256; }
    else               { W = WV; ld = DV; nl0 = n0 - 512; }

    const int t = threadIdx.x;
#pragma unroll
    for (int p = 0; p < 4; p++) {
        const int kl = (t >> 4) + p * 16;
        const int ng = (t & 15) * 4;
        float4 w = *(const float4*)&W[(size_t)(k0 + kl) * ld + nl0 + ng];
        sh[kl][ng + 0] = bf16_rne(w.x);
        sh[kl][ng + 1] = bf16_rne(w.y);
        sh[kl][ng + 2] = bf16_rne(w.z);
        sh[kl][ng + 3] = bf16_rne(w.w);
    }
    __syncthreads();
#pragma unroll
    for (int p = 0; p < 4; p++) {
        const int nl = (t >> 4) + p * 16;
        const int kg = (t & 15) * 4;
        ushort4 h;
        h.x = sh[kg + 0][nl]; h.y = sh[kg + 1][nl];
        h.z = sh[kg + 2][nl]; h.w = sh[kg + 3][nl];
        *(ushort4*)&Bt[(size_t)(n0 + nl) * HID + k0 + kg] = h;
    }
}

// ---------------------------------------------------------------------------
// Kernel 1: QKV projection, bf16 MFMA + xPos epilogue.
// C = X @ [W_Q|W_K|W_V], M=16384, N=1024, K=2048. 128x128 tile, BK=32,
// 512 threads = 8 waves, each wave 64x32 (acc 4x2 = 32 regs, frags 24 regs:
// total ~75 incl addressing -> fits the allocator's ~76-reg unified budget,
// eliminating the 3.7 GB/launch scratch spill seen with 4x4-acc waves).
// ---------------------------------------------------------------------------
__global__ __launch_bounds__(512, 1) void qkv_mfma_kernel(
    const unsigned short* __restrict__ Xb, const unsigned short* __restrict__ Bt,
    unsigned short* __restrict__ Qb, unsigned short* __restrict__ Kb,
    unsigned short* __restrict__ Vb, unsigned short* __restrict__ Vt)
{
    __shared__ unsigned short Ah[128 * 32];
    __shared__ unsigned short Bh[128 * 32];

    // XCD swizzle: 8 n-tiles of one m-tile share bid&7 -> same XCD L2.
    const int bid = blockIdx.x;          // 1024 blocks
    const int xcd = bid & 7;
    const int nt  = (bid >> 3) & 7;      // 8 n-tiles
    const int mt  = (xcd << 4) | (bid >> 6);   // 128 m-tiles
    const int m0 = mt * 128, n0 = nt * 128;

    const int t = threadIdx.x;
    const int w = t >> 6, lane = t & 63;
    const int wm = (w & 1) << 6;         // 0,64
    const int wn = (w >> 1) << 5;        // 0,32,64,96

    floatx4 acc[4][2];
#pragma unroll
    for (int i = 0; i < 4; i++)
#pragma unroll
        for (int j = 0; j < 2; j++) acc[i][j] = (floatx4)0.0f;

    const int srow = lane >> 2, scol = (lane & 3) * 8;
    const size_t aoff = (size_t)(m0 + w * 16 + srow) * HID + scol;
    const size_t boff = (size_t)(n0 + w * 16 + srow) * HID + scol;
    unsigned short* const ldsA = &Ah[(w * 16) * 32];
    unsigned short* const ldsB = &Bh[(w * 16) * 32];

    const int fr = lane & 15, fq = (lane >> 4) * 8;

    for (int k0 = 0; k0 < HID; k0 += 32) {
        __syncthreads();
        gld16(Xb + aoff + k0, ldsA);
        gld16(Bt + boff + k0, ldsB);
        __syncthreads();

        short8 ah[4], bh[2];
#pragma unroll
        for (int i = 0; i < 4; i++)
            ah[i] = *(const short8*)&Ah[(wm + i * 16 + fr) * 32 + fq];
#pragma unroll
        for (int j = 0; j < 2; j++)
            bh[j] = *(const short8*)&Bh[(wn + j * 16 + fr) * 32 + fq];
#pragma unroll
        for (int i = 0; i < 4; i++)
#pragma unroll
            for (int j = 0; j < 2; j++)
                acc[i][j] = __builtin_amdgcn_mfma_f32_16x16x32_bf16(ah[i], bh[j], acc[i][j], 0, 0, 0);
    }

    // epilogue. C/D layout: col = lane&15, row = (lane>>4)*4 + reg.
    const int cl = lane & 15, rq = (lane >> 4) << 2;
    if (n0 >= 512) {
#pragma unroll
        for (int i = 0; i < 4; i++)
#pragma unroll
            for (int j = 0; j < 2; j++) {
                const int c = n0 - 512 + wn + j * 16 + cl;   // dv 0..511
#pragma unroll
                for (int r = 0; r < 4; r++) {
                    const int m = m0 + wm + i * 16 + rq + r;
                    const unsigned short hv = bf16_rne(acc[i][j][r]);
                    Vb[(size_t)m * DV + c] = hv;
                    Vt[(size_t)c * MROWS + m] = hv;
                }
            }
    } else {
        unsigned short* dst = (n0 < 256) ? Qb : Kb;
        const float sgn = (n0 < 256) ? 1.f : -1.f;     // K downscaled
        const int nb = (n0 < 256) ? n0 : n0 - 256;
#pragma unroll
        for (int j = 0; j < 2; j++) {
            const int c = nb + wn + j * 16 + cl;
            const float jj = (float)(c >> 1);
            const float sv = (2.f * jj + 0.4f * 256.f) * (1.f / (1.4f * 256.f));
            const float l2sv = __log2f(sv) * sgn * (1.f / 512.f);
            const float invf = exp2f(jj * (-LOG2_10000 / 128.f));
            const bool odd = (c & 1) != 0;
#pragma unroll
            for (int i = 0; i < 4; i++) {
#pragma unroll
                for (int r = 0; r < 4; r++) {
                    const int m = m0 + wm + i * 16 + rq + r;
                    const float s = (float)(m & (SEQ - 1));
                    const float x = acc[i][j][r];
                    const float p = __shfl_xor(x, 1, 64);   // partner col c^1
                    const float sc = exp2f(s * l2sv);
                    const float ang = s * invf;
                    const float sn = __sinf(ang), cs = __cosf(ang);
                    const float o = odd ? sc * (x * cs + p * sn)
                                        : sc * (x * cs - p * sn);
                    dst[(size_t)m * DH + c] = bf16_rne(o);
                }
            }
        }
    }
}

// ---------------------------------------------------------------------------
// Kernel 2: per-chunk U_c = K^T diag(gamma^(C-i)) V, written TRANSPOSED:
// Ut[b][c][dv(512)][dh(256)] fp32 (B-operand layout for the cross MFMA).
// 64(dh)x128(dv) tile, micro 4x8 (acc 32 regs -> no spill). 2048 blocks.
// ---------------------------------------------------------------------------
__global__ __launch_bounds__(256, 1) void chunk_kv_kernel(
    const unsigned short* __restrict__ Kb, const unsigned short* __restrict__ Vb,
    float* __restrict__ Ut)
{
    __shared__ float kls[32][68];    // [i][dh 64], pre-scaled by gamma^(C-i)
    __shared__ float vls[32][132];   // [i][dv 128]

    const int bid = blockIdx.x;      // 2048
    const int vq = bid & 3;
    const int ht = (bid >> 2) & 3;
    const int c  = (bid >> 4) & 31;
    const int b  = bid >> 9;
    const int dh0 = ht * 64, dv0 = vq * 128;
    const int t = threadIdx.x, tx = t & 15, ty = t >> 4;

    float acc[4][8];
#pragma unroll
    for (int i = 0; i < 4; i++)
#pragma unroll
        for (int j = 0; j < 8; j++) acc[i][j] = 0.f;

    const int klr = t >> 4, klc = (t & 15) << 2;    // K: 16 rows/pass, 2 passes
    const int vlr = t >> 5, vlc = (t & 31) << 2;    // V: 8 rows/pass, 4 passes

    for (int i0 = 0; i0 < CHUNK; i0 += 32) {
        __syncthreads();
#pragma unroll
        for (int p = 0; p < 2; p++) {
            const int il = klr + 16 * p;
            const int i = i0 + il;
            const int row = b * SEQ + c * CHUNK + i;
            const float wgt = exp2f((float)(CHUNK - i) * LOG2_GAMMA);
            ushort4 kq = *(const ushort4*)&Kb[(size_t)row * DH + dh0 + klc];
            kls[il][klc + 0] = b2f(kq.x) * wgt;
            kls[il][klc + 1] = b2f(kq.y) * wgt;
            kls[il][klc + 2] = b2f(kq.z) * wgt;
            kls[il][klc + 3] = b2f(kq.w) * wgt;
        }
#pragma unroll
        for (int p = 0; p < 4; p++) {
            const int il = vlr + 8 * p;
            const int row = b * SEQ + c * CHUNK + i0 + il;
            ushort4 vv = *(const ushort4*)&Vb[(size_t)row * DV + dv0 + vlc];
            vls[il][vlc + 0] = b2f(vv.x);
            vls[il][vlc + 1] = b2f(vv.y);
            vls[il][vlc + 2] = b2f(vv.z);
            vls[il][vlc + 3] = b2f(vv.w);
        }
        __syncthreads();
#pragma unroll
        for (int i = 0; i < 32; i++) {
            float af[4], bf[8];
            *(float4*)&af[0] = *(const float4*)&kls[i][ty * 4];
            *(float4*)&bf[0] = *(const float4*)&vls[i][tx * 8];
            *(float4*)&bf[4] = *(const float4*)&vls[i][tx * 8 + 4];
#pragma unroll
            for (int ii = 0; ii < 4; ii++)
#pragma unroll
                for (int jj = 0; jj < 8; jj++) acc[ii][jj] += af[ii] * bf[jj];
        }
    }

    // transposed store: Ut[((b*32+c)*512 + dv)*256 + dh]
#pragma unroll
    for (int jj = 0; jj < 8; jj++) {
        const int dv = dv0 + tx * 8 + jj;
        const size_t base = ((size_t)(b * NCH + c) * DV + dv) * DH + dh0 + ty * 4;
        *(float4*)&Ut[base] = make_float4(acc[0][jj], acc[1][jj], acc[2][jj], acc[3][jj]);
    }
}

// ---------------------------------------------------------------------------
// Kernel 3: exclusive scan over chunks: Ut[c] <- S_c (state BEFORE chunk c).
// Layout-agnostic elementwise scan over the 131072 per-(b,c) entries.
// ---------------------------------------------------------------------------
__global__ __launch_bounds__(256) void scan_kernel(float* __restrict__ Ut)
{
    const int t = blockIdx.x * 256 + threadIdx.x;   // 0..524287
    const int b = t >> 17;                          // DV*DH = 131072
    const int r = t & 131071;
    const float gC = exp2f((float)CHUNK * LOG2_GAMMA);
    float s = 0.f;
    const size_t base = (size_t)b * NCH * 131072 + r;
    for (int c = 0; c < NCH; c++) {
        const size_t off = base + (size_t)c * 131072;
        const float u = Ut[off];
        Ut[off] = s;
        s = gC * s + u;
    }
}

// ---------------------------------------------------------------------------
// Kernel 4: O = (tril(QK^T) .* gamma^(i-j)) @ V  +  (gamma^i Q) @ S_c^T.
// Full bf16 MFMA, 512 threads = 8 waves, each wave 64x32 (acc 32 regs).
// Block = (b, chunk, dv-quarter): 128(i) x 128(dv) output.
// ---------------------------------------------------------------------------
__global__ __launch_bounds__(512, 1) void out_mfma_kernel(
    const unsigned short* __restrict__ Qb, const unsigned short* __restrict__ Kb,
    const unsigned short* __restrict__ Vt, const float* __restrict__ St,
    float* __restrict__ out)
{
    __shared__ unsigned short Pa[128 * 136];   // P bf16, row stride 136 (pad)
    __shared__ unsigned short As[128 * 32];
    __shared__ unsigned short Bs[128 * 32];

    const int bid = blockIdx.x;      // 512
    const int vq = bid & 3;
    const int c  = (bid >> 2) & 31;
    const int b  = bid >> 7;
    const int dv0 = vq * 128;
    const int row0 = b * SEQ + c * CHUNK;

    const int t = threadIdx.x;
    const int w = t >> 6, lane = t & 63;
    const int wm = (w & 1) << 6;         // 0,64
    const int wn = (w >> 1) << 5;        // 0,32,64,96
    const int fr = lane & 15, fq = (lane >> 4) * 8;
    const int cl = lane & 15, rq = (lane >> 4) << 2;
    const int srow = lane >> 2, scol = (lane & 3) * 8;

    floatx4 acc[4][2];
#pragma unroll
    for (int i = 0; i < 4; i++)
#pragma unroll
        for (int j = 0; j < 2; j++) acc[i][j] = (floatx4)0.0f;

    // ---------------- phase 1: P = Q K^T ----------------
    for (int d0 = 0; d0 < DH; d0 += 32) {
        __syncthreads();
        gld16(&Qb[(size_t)(row0 + w * 16 + srow) * DH + d0 + scol], &As[(w * 16) * 32]);
        gld16(&Kb[(size_t)(row0 + w * 16 + srow) * DH + d0 + scol], &Bs[(w * 16) * 32]);
        __syncthreads();
        short8 a[4], bb[2];
#pragma unroll
        for (int i = 0; i < 4; i++)
            a[i] = *(const short8*)&As[(wm + i * 16 + fr) * 32 + fq];
#pragma unroll
        for (int j = 0; j < 2; j++)
            bb[j] = *(const short8*)&Bs[(wn + j * 16 + fr) * 32 + fq];
#pragma unroll
        for (int i = 0; i < 4; i++)
#pragma unroll
            for (int j = 0; j < 2; j++)
                acc[i][j] = __builtin_amdgcn_mfma_f32_16x16x32_bf16(a[i], bb[j], acc[i][j], 0, 0, 0);
    }

    // decay mask + bf16 -> Pa[i][j] (i = q row in chunk, j = k row)
#pragma unroll
    for (int i = 0; i < 4; i++)
#pragma unroll
        for (int j = 0; j < 2; j++) {
            const int jj = wn + j * 16 + cl;
#pragma unroll
            for (int r = 0; r < 4; r++) {
                const int ii = wm + i * 16 + rq + r;
                const int diff = ii - jj;
                const float v = (diff >= 0) ? acc[i][j][r] * exp2f((float)diff * LOG2_GAMMA) : 0.f;
                Pa[ii * 136 + jj] = bf16_rne(v);
            }
            acc[i][j] = (floatx4)0.0f;     // reset for O accumulation
        }

    // ---------------- phase 2: acc = P @ V ----------------
    for (int k0 = 0; k0 < CHUNK; k0 += 32) {
        __syncthreads();   // first iter: Pa visible; later: Bs reads done
        gld16(&Vt[(size_t)(dv0 + w * 16 + srow) * MROWS + row0 + k0 + scol], &Bs[(w * 16) * 32]);
        __syncthreads();
        short8 a[4], bb[2];
#pragma unroll
        for (int i = 0; i < 4; i++)
            a[i] = *(const short8*)&Pa[(wm + i * 16 + fr) * 136 + k0 + fq];
#pragma unroll
        for (int j = 0; j < 2; j++)
            bb[j] = *(const short8*)&Bs[(wn + j * 16 + fr) * 32 + fq];
#pragma unroll
        for (int i = 0; i < 4; i++)
#pragma unroll
            for (int j = 0; j < 2; j++)
                acc[i][j] = __builtin_amdgcn_mfma_f32_16x16x32_bf16(a[i], bb[j], acc[i][j], 0, 0, 0);
    }

    // ---------------- phase 3: acc += (gamma^i Q) @ St ----------------
    const size_t stbase = ((size_t)(b * NCH + c) * DV + dv0) * DH;
    const int xr = t >> 2, xc = (t & 3) * 8;     // 128 rows x 32 cols, 8/thread
    const float gx = exp2f((float)xr * LOG2_GAMMA);   // gamma^i for Q staging
    for (int d0 = 0; d0 < DH; d0 += 32) {
        __syncthreads();
        {
            ushort4 q0 = *(const ushort4*)&Qb[(size_t)(row0 + xr) * DH + d0 + xc];
            ushort4 q1 = *(const ushort4*)&Qb[(size_t)(row0 + xr) * DH + d0 + xc + 4];
            ushort4 h0, h1;
            h0.x = bf16_rne(b2f(q0.x) * gx); h0.y = bf16_rne(b2f(q0.y) * gx);
            h0.z = bf16_rne(b2f(q0.z) * gx); h0.w = bf16_rne(b2f(q0.w) * gx);
            h1.x = bf16_rne(b2f(q1.x) * gx); h1.y = bf16_rne(b2f(q1.y) * gx);
            h1.z = bf16_rne(b2f(q1.z) * gx); h1.w = bf16_rne(b2f(q1.w) * gx);
            *(ushort4*)&As[xr * 32 + xc] = h0;
            *(ushort4*)&As[xr * 32 + xc + 4] = h1;
        }
        {
            float4 s0 = *(const float4*)&St[stbase + (size_t)xr * DH + d0 + xc];
            float4 s1 = *(const float4*)&St[stbase + (size_t)xr * DH + d0 + xc + 4];
            ushort4 h0, h1;
            h0.x = bf16_rne(s0.x); h0.y = bf16_rne(s0.y);
            h0.z = bf16_rne(s0.z); h0.w = bf16_rne(s0.w);
            h1.x = bf16_rne(s1.x); h1.y = bf16_rne(s1.y);
            h1.z = bf16_rne(s1.z); h1.w = bf16_rne(s1.w);
            *(ushort4*)&Bs[xr * 32 + xc] = h0;
            *(ushort4*)&Bs[xr * 32 + xc + 4] = h1;
        }
        __syncthreads();
        short8 a[4], bb[2];
#pragma unroll
        for (int i = 0; i < 4; i++)
            a[i] = *(const short8*)&As[(wm + i * 16 + fr) * 32 + fq];
#pragma unroll
        for (int j = 0; j < 2; j++)
            bb[j] = *(const short8*)&Bs[(wn + j * 16 + fr) * 32 + fq];
#pragma unroll
        for (int i = 0; i < 4; i++)
#pragma unroll
            for (int j = 0; j < 2; j++)
                acc[i][j] = __builtin_amdgcn_mfma_f32_16x16x32_bf16(a[i], bb[j], acc[i][j], 0, 0, 0);
    }

    // epilogue: fp32 store
#pragma unroll
    for (int i = 0; i < 4; i++)
#pragma unroll
        for (int j = 0; j < 2; j++) {
            const int dv = dv0 + wn + j * 16 + cl;
#pragma unroll
            for (int r = 0; r < 4; r++) {
                const int m = row0 + wm + i * 16 + rq + r;
                out[(size_t)m * DV + dv] = acc[i][j][r];
            }
        }
}

// ---------------------------------------------------------------------------
extern "C" void kernel_launch(void* const* d_in, const int* in_sizes, int n_in,
                              void* d_out, int out_size, void* d_ws, size_t ws_size,
                              hipStream_t stream) {
    const float* X  = (const float*)d_in[0];
    const float* WQ = (const float*)d_in[1];
    const float* WK = (const float*)d_in[2];
    const float* WV = (const float*)d_in[3];
    float* out = (float*)d_out;

    // Workspace layout:
    //   Qb 8.4MB | Kb 8.4MB | Vb 16.8MB | Vt 16.8MB | Ut 67.1MB (fp32)
    //   Xb bf16 67.1MB OVERLAPS Ut (Xb dead after qkv; Ut written after)
    //   Bt bf16 4.2MB. Total ~122 MB.
    char* ws = (char*)d_ws;
    unsigned short* Qb = (unsigned short*)ws;
    unsigned short* Kb = Qb + (size_t)MROWS * DH;
    unsigned short* Vb = Kb + (size_t)MROWS * DH;
    unsigned short* Vt = Vb + (size_t)MROWS * DV;
    float*          Ut = (float*)(Vt + (size_t)MROWS * DV);
    unsigned short* Xb = (unsigned short*)Ut;       // overlap
    unsigned short* Bt = (unsigned short*)(Ut + (size_t)NB * NCH * DV * DH);

    xcvt_kernel<<<(MROWS * HID / 4) / 256, 256, 0, stream>>>(X, Xb);
    wcvt_kernel<<<512, 256, 0, stream>>>(WQ, WK, WV, Bt);
    qkv_mfma_kernel<<<1024, 512, 0, stream>>>(Xb, Bt, Qb, Kb, Vb, Vt);
    chunk_kv_kernel<<<2048, 256, 0, stream>>>(Kb, Vb, Ut);
    scan_kernel<<<2048, 256, 0, stream>>>(Ut);
    out_mfma_kernel<<<512, 512, 0, stream>>>(Qb, Kb, Vt, Ut, out);
}

// Round 6
// 371.452 us; speedup vs baseline: 5.8348x; 1.1162x over previous
//
#include <hip/hip_runtime.h>
#include <math.h>

#define NB 4
#define SEQ 4096
#define HID 2048
#define DH 256
#define DV 512
#define NQKV 1024               // DH + DH + DV packed
#define CHUNK 128
#define NCH 32                  // SEQ/CHUNK
#define MROWS (NB * SEQ)        // 16384
#define GAMMA 0.96875f
#define GAMMA_INV 1.0322580645161290f
// log2(0.96875)
#define LOG2_GAMMA (-0.045803689613124794f)
// log2(10000)
#define LOG2_10000 13.287712379549449f

typedef __attribute__((ext_vector_type(8))) short short8;
typedef __attribute__((ext_vector_type(4))) float floatx4;

// ---------------------------------------------------------------------------
// helpers
// ---------------------------------------------------------------------------
__device__ __forceinline__ unsigned short bf16_rne(float v) {
    unsigned int u = __float_as_uint(v);
    u += 0x7fff + ((u >> 16) & 1);
    return (unsigned short)(u >> 16);
}
__device__ __forceinline__ float b2f(unsigned short h) {
    return __uint_as_float((unsigned int)h << 16);
}

// async global->LDS, 16 bytes per lane. LDS dest = wave-uniform base + lane*16.
__device__ __forceinline__ void gld16(const void* g, void* l) {
    __builtin_amdgcn_global_load_lds(
        reinterpret_cast<const __attribute__((address_space(1))) unsigned int*>(
            reinterpret_cast<uintptr_t>(g)),
        reinterpret_cast<__attribute__((address_space(3))) unsigned int*>(
            reinterpret_cast<uintptr_t>(l)),
        16, 0, 0);
}

// ---------------------------------------------------------------------------
// Kernel 0a: X fp32 -> bf16 row-major [M][K].
// ---------------------------------------------------------------------------
__global__ __launch_bounds__(256) void xcvt_kernel(
    const float* __restrict__ X, unsigned short* __restrict__ Xb)
{
    const int i = blockIdx.x * 256 + threadIdx.x;   // one float4 per thread
    float4 x = ((const float4*)X)[i];
    ushort4 h;
    h.x = bf16_rne(x.x); h.y = bf16_rne(x.y);
    h.z = bf16_rne(x.z); h.w = bf16_rne(x.w);
    ((ushort4*)Xb)[i] = h;
}

// ---------------------------------------------------------------------------
// Kernel 0b: W_Q|W_K|W_V fp32 [K][Nregion] -> transposed packed bf16 Bt[n][k].
// ---------------------------------------------------------------------------
__global__ __launch_bounds__(256) void wcvt_kernel(
    const float* __restrict__ WQ, const float* __restrict__ WK,
    const float* __restrict__ WV, unsigned short* __restrict__ Bt)
{
    __shared__ unsigned short sh[64][65];
    const int bid = blockIdx.x;         // 32 k-tiles * 16 n-tiles
    const int kt = bid & 31;
    const int ntile = bid >> 5;
    const int k0 = kt * 64, n0 = ntile * 64;

    const float* W; int ld, nl0;
    if (n0 < 256)      { W = WQ; ld = DH; nl0 = n0; }
    else if (n0 < 512) { W = WK; ld = DH; nl0 = n0 - 256; }
    else               { W = WV; ld = DV; nl0 = n0 - 512; }

    const int t = threadIdx.x;
#pragma unroll
    for (int p = 0; p < 4; p++) {
        const int kl = (t >> 4) + p * 16;
        const int ng = (t & 15) * 4;
        float4 w = *(const float4*)&W[(size_t)(k0 + kl) * ld + nl0 + ng];
        sh[kl][ng + 0] = bf16_rne(w.x);
        sh[kl][ng + 1] = bf16_rne(w.y);
        sh[kl][ng + 2] = bf16_rne(w.z);
        sh[kl][ng + 3] = bf16_rne(w.w);
    }
    __syncthreads();
#pragma unroll
    for (int p = 0; p < 4; p++) {
        const int nl = (t >> 4) + p * 16;
        const int kg = (t & 15) * 4;
        ushort4 h;
        h.x = sh[kg + 0][nl]; h.y = sh[kg + 1][nl];
        h.z = sh[kg + 2][nl]; h.w = sh[kg + 3][nl];
        *(ushort4*)&Bt[(size_t)(n0 + nl) * HID + k0 + kg] = h;
    }
}

// ---------------------------------------------------------------------------
// Kernel 1: QKV projection, bf16 MFMA + xPos epilogue.
// M=16384, N=1024, K=2048. 128x128 tile, BK=64 (two 32-wide LDS halves,
// inner half-loop NOT unrolled to keep frag live-set at 24 VGPRs -> no
// spill under the allocator's ~76-reg unified budget; see round 2-5 saga).
// 512 threads = 8 waves, wave tile 64x32, acc 4x2 floatx4 = 32 regs.
// Outputs (bf16): Qb[m][256], Kb[m][256], Kt[dh][m], Vt[dv][m].
// ---------------------------------------------------------------------------
__global__ __launch_bounds__(512, 1) void qkv_mfma_kernel(
    const unsigned short* __restrict__ Xb, const unsigned short* __restrict__ Bt,
    unsigned short* __restrict__ Qb, unsigned short* __restrict__ Kb,
    unsigned short* __restrict__ Kt, unsigned short* __restrict__ Vt)
{
    __shared__ unsigned short Ah[2 * 128 * 32];
    __shared__ unsigned short Bh[2 * 128 * 32];

    // XCD swizzle: 8 n-tiles of one m-tile share bid&7 -> same XCD L2.
    const int bid = blockIdx.x;          // 1024 blocks
    const int xcd = bid & 7;
    const int nt  = (bid >> 3) & 7;      // 8 n-tiles
    const int mt  = (xcd << 4) | (bid >> 6);   // 128 m-tiles
    const int m0 = mt * 128, n0 = nt * 128;

    const int t = threadIdx.x;
    const int w = t >> 6, lane = t & 63;
    const int wm = (w & 1) << 6;         // 0,64
    const int wn = (w >> 1) << 5;        // 0,32,64,96

    floatx4 acc[4][2];
#pragma unroll
    for (int i = 0; i < 4; i++)
#pragma unroll
        for (int j = 0; j < 2; j++) acc[i][j] = (floatx4)0.0f;

    const int srow = lane >> 2, scol = (lane & 3) * 8;
    const size_t aoff = (size_t)(m0 + w * 16 + srow) * HID + scol;
    const size_t boff = (size_t)(n0 + w * 16 + srow) * HID + scol;
    unsigned short* const ldsA0 = &Ah[(w * 16) * 32];
    unsigned short* const ldsA1 = &Ah[4096 + (w * 16) * 32];
    unsigned short* const ldsB0 = &Bh[(w * 16) * 32];
    unsigned short* const ldsB1 = &Bh[4096 + (w * 16) * 32];

    const int fr = lane & 15, fq = (lane >> 4) * 8;

    for (int k0 = 0; k0 < HID; k0 += 64) {
        __syncthreads();
        gld16(Xb + aoff + k0,      ldsA0);
        gld16(Xb + aoff + k0 + 32, ldsA1);
        gld16(Bt + boff + k0,      ldsB0);
        gld16(Bt + boff + k0 + 32, ldsB1);
        __syncthreads();

#pragma nounroll
        for (int s = 0; s < 2; s++) {
            short8 ah[4], bh[2];
#pragma unroll
            for (int i = 0; i < 4; i++)
                ah[i] = *(const short8*)&Ah[s * 4096 + (wm + i * 16 + fr) * 32 + fq];
#pragma unroll
            for (int j = 0; j < 2; j++)
                bh[j] = *(const short8*)&Bh[s * 4096 + (wn + j * 16 + fr) * 32 + fq];
#pragma unroll
            for (int i = 0; i < 4; i++)
#pragma unroll
                for (int j = 0; j < 2; j++)
                    acc[i][j] = __builtin_amdgcn_mfma_f32_16x16x32_bf16(ah[i], bh[j], acc[i][j], 0, 0, 0);
        }
    }

    // epilogue. C/D layout: col = lane&15, row = (lane>>4)*4 + reg.
    const int cl = lane & 15, rq = (lane >> 4) << 2;
    if (n0 >= 512) {
#pragma unroll
        for (int i = 0; i < 4; i++)
#pragma unroll
            for (int j = 0; j < 2; j++) {
                const int c = n0 - 512 + wn + j * 16 + cl;   // dv 0..511
#pragma unroll
                for (int r = 0; r < 4; r++) {
                    const int m = m0 + wm + i * 16 + rq + r;
                    Vt[(size_t)c * MROWS + m] = bf16_rne(acc[i][j][r]);
                }
            }
    } else {
        const bool isQ = (n0 < 256);
        unsigned short* dst = isQ ? Qb : Kb;
        const float sgn = isQ ? 1.f : -1.f;     // K downscaled
        const int nb = isQ ? n0 : n0 - 256;
#pragma unroll
        for (int j = 0; j < 2; j++) {
            const int c = nb + wn + j * 16 + cl;
            const float jj = (float)(c >> 1);
            const float sv = (2.f * jj + 0.4f * 256.f) * (1.f / (1.4f * 256.f));
            const float l2sv = __log2f(sv) * sgn * (1.f / 512.f);
            const float invf = exp2f(jj * (-LOG2_10000 / 128.f));
            const bool odd = (c & 1) != 0;
#pragma unroll
            for (int i = 0; i < 4; i++) {
#pragma unroll
                for (int r = 0; r < 4; r++) {
                    const int m = m0 + wm + i * 16 + rq + r;
                    const float s = (float)(m & (SEQ - 1));
                    const float x = acc[i][j][r];
                    const float p = __shfl_xor(x, 1, 64);   // partner col c^1
                    const float sc = exp2f(s * l2sv);
                    const float ang = s * invf;
                    const float sn = __sinf(ang), cs = __cosf(ang);
                    const float o = odd ? sc * (x * cs + p * sn)
                                        : sc * (x * cs - p * sn);
                    const unsigned short hv = bf16_rne(o);
                    dst[(size_t)m * DH + c] = hv;
                    if (!isQ) Kt[(size_t)c * MROWS + m] = hv;
                }
            }
        }
    }
}

// ---------------------------------------------------------------------------
// Kernel 2: per-chunk U_c^T = V^T diag(gamma^(C-i)) K, via bf16 MFMA.
// C[m=dv][n=dh] = sum_i Vt[dv][i] * (gamma^(C-i) Kt[dh][i]).
// Output Ut[b][c][dv 512][dh 256] fp32. Block = 128(dv) x 128(dh), K=128,
// 512 threads / 8 waves, wave 64x32. Grid = 4*32*4*2 = 1024.
// ---------------------------------------------------------------------------
__global__ __launch_bounds__(512, 1) void chunk_kv_kernel(
    const unsigned short* __restrict__ Kt, const unsigned short* __restrict__ Vt,
    float* __restrict__ Ut)
{
    __shared__ unsigned short As[128 * 32];   // Vt rows (dv) x i
    __shared__ unsigned short Bs[128 * 32];   // scaled Kt rows (dh) x i

    const int bid = blockIdx.x;      // 1024
    const int dht = bid & 1;
    const int vq  = (bid >> 1) & 3;
    const int c   = (bid >> 3) & 31;
    const int b   = bid >> 8;
    const int dh0 = dht * 128, dv0 = vq * 128;
    const int row0 = b * SEQ + c * CHUNK;

    const int t = threadIdx.x;
    const int w = t >> 6, lane = t & 63;
    const int wm = (w & 1) << 6;         // dv offset
    const int wn = (w >> 1) << 5;        // dh offset
    const int srow = lane >> 2, scol = (lane & 3) * 8;
    const int fr = lane & 15, fq = (lane >> 4) * 8;

    floatx4 acc[4][2];
#pragma unroll
    for (int i = 0; i < 4; i++)
#pragma unroll
        for (int j = 0; j < 2; j++) acc[i][j] = (floatx4)0.0f;

    const int kr = t >> 2, kc = (t & 3) * 8;   // B staging: 128 rows x 32 cols

    for (int i0 = 0; i0 < CHUNK; i0 += 32) {
        __syncthreads();
        gld16(&Vt[(size_t)(dv0 + w * 16 + srow) * MROWS + row0 + i0 + scol],
              &As[(w * 16) * 32]);
        {
            const unsigned short* src = &Kt[(size_t)(dh0 + kr) * MROWS + row0 + i0 + kc];
            ushort4 k0v = *(const ushort4*)src;
            ushort4 k1v = *(const ushort4*)(src + 4);
            float g = exp2f((float)(CHUNK - i0 - kc) * LOG2_GAMMA);  // gamma^(C-i)
            ushort4 h0, h1;
            h0.x = bf16_rne(b2f(k0v.x) * g); g *= GAMMA_INV;
            h0.y = bf16_rne(b2f(k0v.y) * g); g *= GAMMA_INV;
            h0.z = bf16_rne(b2f(k0v.z) * g); g *= GAMMA_INV;
            h0.w = bf16_rne(b2f(k0v.w) * g); g *= GAMMA_INV;
            h1.x = bf16_rne(b2f(k1v.x) * g); g *= GAMMA_INV;
            h1.y = bf16_rne(b2f(k1v.y) * g); g *= GAMMA_INV;
            h1.z = bf16_rne(b2f(k1v.z) * g); g *= GAMMA_INV;
            h1.w = bf16_rne(b2f(k1v.w) * g);
            *(ushort4*)&Bs[kr * 32 + kc] = h0;
            *(ushort4*)&Bs[kr * 32 + kc + 4] = h1;
        }
        __syncthreads();
        short8 a[4], bb[2];
#pragma unroll
        for (int i = 0; i < 4; i++)
            a[i] = *(const short8*)&As[(wm + i * 16 + fr) * 32 + fq];
#pragma unroll
        for (int j = 0; j < 2; j++)
            bb[j] = *(const short8*)&Bs[(wn + j * 16 + fr) * 32 + fq];
#pragma unroll
        for (int i = 0; i < 4; i++)
#pragma unroll
            for (int j = 0; j < 2; j++)
                acc[i][j] = __builtin_amdgcn_mfma_f32_16x16x32_bf16(a[i], bb[j], acc[i][j], 0, 0, 0);
    }

    // store: C[m=dv][n=dh] -> Ut[((b*32+c)*512 + dv0+m)*256 + dh0+n]
    const int cl = lane & 15, rq = (lane >> 4) << 2;
    const size_t ubase = ((size_t)(b * NCH + c) * DV + dv0) * DH + dh0;
#pragma unroll
    for (int i = 0; i < 4; i++)
#pragma unroll
        for (int j = 0; j < 2; j++) {
            const int n = wn + j * 16 + cl;
#pragma unroll
            for (int r = 0; r < 4; r++) {
                const int m = wm + i * 16 + rq + r;
                Ut[ubase + (size_t)m * DH + n] = acc[i][j][r];
            }
        }
}

// ---------------------------------------------------------------------------
// Kernel 3: exclusive scan over chunks; emits bf16 state Sb[c] = S_c
// (state BEFORE chunk c), layout [b][c][dv][dh] (B-operand-ready).
// ---------------------------------------------------------------------------
__global__ __launch_bounds__(256) void scan_kernel(
    const float* __restrict__ Ut, unsigned short* __restrict__ Sb)
{
    const int t = blockIdx.x * 256 + threadIdx.x;   // 0..524287
    const int b = t >> 17;                          // DV*DH = 131072
    const int r = t & 131071;
    const float gC = exp2f((float)CHUNK * LOG2_GAMMA);
    float s = 0.f;
    const size_t base = (size_t)b * NCH * 131072 + r;
    for (int c = 0; c < NCH; c++) {
        const size_t off = base + (size_t)c * 131072;
        const float u = Ut[off];
        Sb[off] = bf16_rne(s);
        s = gC * s + u;
    }
}

// ---------------------------------------------------------------------------
// Kernel 4: O = (tril(QK^T) .* gamma^(i-j)) @ V  +  (gamma^i Q) @ S_c^T.
// Full bf16 MFMA, 512 threads = 8 waves, wave 64x32. BK=64 in phases 1/3.
// Block = (b, chunk, dv-quarter): 128(i) x 128(dv) output. Grid = 512.
// ---------------------------------------------------------------------------
__global__ __launch_bounds__(512, 1) void out_mfma_kernel(
    const unsigned short* __restrict__ Qb, const unsigned short* __restrict__ Kb,
    const unsigned short* __restrict__ Vt, const unsigned short* __restrict__ Sb,
    float* __restrict__ out)
{
    __shared__ unsigned short Pa[128 * 136];   // P bf16, row stride 136 (pad)
    __shared__ unsigned short As[2 * 128 * 32];
    __shared__ unsigned short Bs[2 * 128 * 32];

    const int bid = blockIdx.x;      // 512
    const int vq = bid & 3;
    const int c  = (bid >> 2) & 31;
    const int b  = bid >> 7;
    const int dv0 = vq * 128;
    const int row0 = b * SEQ + c * CHUNK;

    const int t = threadIdx.x;
    const int w = t >> 6, lane = t & 63;
    const int wm = (w & 1) << 6;         // 0,64
    const int wn = (w >> 1) << 5;        // 0,32,64,96
    const int fr = lane & 15, fq = (lane >> 4) * 8;
    const int cl = lane & 15, rq = (lane >> 4) << 2;
    const int srow = lane >> 2, scol = (lane & 3) * 8;

    floatx4 acc[4][2];
#pragma unroll
    for (int i = 0; i < 4; i++)
#pragma unroll
        for (int j = 0; j < 2; j++) acc[i][j] = (floatx4)0.0f;

    // ---------------- phase 1: P = Q K^T (BK=64) ----------------
    for (int d0 = 0; d0 < DH; d0 += 64) {
        __syncthreads();
        gld16(&Qb[(size_t)(row0 + w * 16 + srow) * DH + d0 + scol], &As[(w * 16) * 32]);
        gld16(&Qb[(size_t)(row0 + w * 16 + srow) * DH + d0 + 32 + scol], &As[4096 + (w * 16) * 32]);
        gld16(&Kb[(size_t)(row0 + w * 16 + srow) * DH + d0 + scol], &Bs[(w * 16) * 32]);
        gld16(&Kb[(size_t)(row0 + w * 16 + srow) * DH + d0 + 32 + scol], &Bs[4096 + (w * 16) * 32]);
        __syncthreads();
#pragma nounroll
        for (int s = 0; s < 2; s++) {
            short8 a[4], bb[2];
#pragma unroll
            for (int i = 0; i < 4; i++)
                a[i] = *(const short8*)&As[s * 4096 + (wm + i * 16 + fr) * 32 + fq];
#pragma unroll
            for (int j = 0; j < 2; j++)
                bb[j] = *(const short8*)&Bs[s * 4096 + (wn + j * 16 + fr) * 32 + fq];
#pragma unroll
            for (int i = 0; i < 4; i++)
#pragma unroll
                for (int j = 0; j < 2; j++)
                    acc[i][j] = __builtin_amdgcn_mfma_f32_16x16x32_bf16(a[i], bb[j], acc[i][j], 0, 0, 0);
        }
    }

    // decay mask + bf16 -> Pa[i][j] (i = q row in chunk, j = k row)
#pragma unroll
    for (int i = 0; i < 4; i++)
#pragma unroll
        for (int j = 0; j < 2; j++) {
            const int jj = wn + j * 16 + cl;
#pragma unroll
            for (int r = 0; r < 4; r++) {
                const int ii = wm + i * 16 + rq + r;
                const int diff = ii - jj;
                const float v = (diff >= 0) ? acc[i][j][r] * exp2f((float)diff * LOG2_GAMMA) : 0.f;
                Pa[ii * 136 + jj] = bf16_rne(v);
            }
            acc[i][j] = (floatx4)0.0f;     // reset for O accumulation
        }

    // ---------------- phase 2: acc = P @ V (BK=64, K=128 total) ----------
    for (int k0 = 0; k0 < CHUNK; k0 += 64) {
        __syncthreads();   // first iter: Pa visible; later: Bs reads done
        gld16(&Vt[(size_t)(dv0 + w * 16 + srow) * MROWS + row0 + k0 + scol], &Bs[(w * 16) * 32]);
        gld16(&Vt[(size_t)(dv0 + w * 16 + srow) * MROWS + row0 + k0 + 32 + scol], &Bs[4096 + (w * 16) * 32]);
        __syncthreads();
#pragma nounroll
        for (int s = 0; s < 2; s++) {
            short8 a[4], bb[2];
#pragma unroll
            for (int i = 0; i < 4; i++)
                a[i] = *(const short8*)&Pa[(wm + i * 16 + fr) * 136 + k0 + s * 32 + fq];
#pragma unroll
            for (int j = 0; j < 2; j++)
                bb[j] = *(const short8*)&Bs[s * 4096 + (wn + j * 16 + fr) * 32 + fq];
#pragma unroll
            for (int i = 0; i < 4; i++)
#pragma unroll
                for (int j = 0; j < 2; j++)
                    acc[i][j] = __builtin_amdgcn_mfma_f32_16x16x32_bf16(a[i], bb[j], acc[i][j], 0, 0, 0);
        }
    }

    // ---------------- phase 3: acc += (gamma^i Q) @ Sb (BK=64) ------------
    const size_t sbbase = ((size_t)(b * NCH + c) * DV + dv0) * DH;
    const int xr = t >> 2, xc = (t & 3) * 8;     // A staging: 128 rows x 32 cols
    const float gx = exp2f((float)xr * LOG2_GAMMA);   // gamma^i
    for (int d0 = 0; d0 < DH; d0 += 64) {
        __syncthreads();
#pragma unroll
        for (int s = 0; s < 2; s++) {
            const unsigned short* src = &Qb[(size_t)(row0 + xr) * DH + d0 + s * 32 + xc];
            ushort4 q0 = *(const ushort4*)src;
            ushort4 q1 = *(const ushort4*)(src + 4);
            ushort4 h0, h1;
            h0.x = bf16_rne(b2f(q0.x) * gx); h0.y = bf16_rne(b2f(q0.y) * gx);
            h0.z = bf16_rne(b2f(q0.z) * gx); h0.w = bf16_rne(b2f(q0.w) * gx);
            h1.x = bf16_rne(b2f(q1.x) * gx); h1.y = bf16_rne(b2f(q1.y) * gx);
            h1.z = bf16_rne(b2f(q1.z) * gx); h1.w = bf16_rne(b2f(q1.w) * gx);
            *(ushort4*)&As[s * 4096 + xr * 32 + xc] = h0;
            *(ushort4*)&As[s * 4096 + xr * 32 + xc + 4] = h1;
        }
        gld16(&Sb[sbbase + (size_t)(w * 16 + srow) * DH + d0 + scol], &Bs[(w * 16) * 32]);
        gld16(&Sb[sbbase + (size_t)(w * 16 + srow) * DH + d0 + 32 + scol], &Bs[4096 + (w * 16) * 32]);
        __syncthreads();
#pragma nounroll
        for (int s = 0; s < 2; s++) {
            short8 a[4], bb[2];
#pragma unroll
            for (int i = 0; i < 4; i++)
                a[i] = *(const short8*)&As[s * 4096 + (wm + i * 16 + fr) * 32 + fq];
#pragma unroll
            for (int j = 0; j < 2; j++)
                bb[j] = *(const short8*)&Bs[s * 4096 + (wn + j * 16 + fr) * 32 + fq];
#pragma unroll
            for (int i = 0; i < 4; i++)
#pragma unroll
                for (int j = 0; j < 2; j++)
                    acc[i][j] = __builtin_amdgcn_mfma_f32_16x16x32_bf16(a[i], bb[j], acc[i][j], 0, 0, 0);
        }
    }

    // epilogue: fp32 store
#pragma unroll
    for (int i = 0; i < 4; i++)
#pragma unroll
        for (int j = 0; j < 2; j++) {
            const int dv = dv0 + wn + j * 16 + cl;
#pragma unroll
            for (int r = 0; r < 4; r++) {
                const int m = row0 + wm + i * 16 + rq + r;
                out[(size_t)m * DV + dv] = acc[i][j][r];
            }
        }
}

// ---------------------------------------------------------------------------
extern "C" void kernel_launch(void* const* d_in, const int* in_sizes, int n_in,
                              void* d_out, int out_size, void* d_ws, size_t ws_size,
                              hipStream_t stream) {
    const float* X  = (const float*)d_in[0];
    const float* WQ = (const float*)d_in[1];
    const float* WK = (const float*)d_in[2];
    const float* WV = (const float*)d_in[3];
    float* out = (float*)d_out;

    // Workspace layout (bf16 unless noted):
    //   Qb 8.4 | Kb 8.4 | Kt 8.4 | Vt 16.8 | Sb 33.5 | Ut fp32 67.1 | Bt 4.2
    //   Xb (67.1) OVERLAPS Ut (Xb dead after qkv; Ut written after). ~147 MB.
    char* ws = (char*)d_ws;
    unsigned short* Qb = (unsigned short*)ws;
    unsigned short* Kb = Qb + (size_t)MROWS * DH;
    unsigned short* Kt = Kb + (size_t)MROWS * DH;
    unsigned short* Vt = Kt + (size_t)MROWS * DH;
    unsigned short* Sb = Vt + (size_t)MROWS * DV;
    float*          Ut = (float*)(Sb + (size_t)NB * NCH * DV * DH);
    unsigned short* Xb = (unsigned short*)Ut;       // overlap
    unsigned short* Bt = (unsigned short*)(Ut + (size_t)NB * NCH * DV * DH);

    xcvt_kernel<<<(MROWS * HID / 4) / 256, 256, 0, stream>>>(X, Xb);
    wcvt_kernel<<<512, 256, 0, stream>>>(WQ, WK, WV, Bt);
    qkv_mfma_kernel<<<1024, 512, 0, stream>>>(Xb, Bt, Qb, Kb, Kt, Vt);
    chunk_kv_kernel<<<1024, 512, 0, stream>>>(Kt, Vt, Ut);
    scan_kernel<<<2048, 256, 0, stream>>>(Ut, Sb);
    out_mfma_kernel<<<512, 512, 0, stream>>>(Qb, Kb, Vt, Sb, out);
}